// Round 2
// baseline (567.774 us; speedup 1.0000x reference)
//
#include <hip/hip_runtime.h>

#define N_NODES   100000
#define N_EDGES   1600000
#define F         128
#define N_CLASSES 47
#define SCAN_B    98   // ceil(N_NODES / 1024)

#define NGRP      8
#define GDIV      12500          // nodes per XCD group
#define GCAP      220000         // staging capacity per group (expect ~200K +- 0.5K)
#define EPT       8              // edges per thread in partition
#define PART_T    256
#define EPB       (PART_T * EPT) // 2048 edges per block
#define PART_B    ((N_EDGES + EPB - 1) / EPB)

typedef unsigned int uint32;

typedef short  v8s __attribute__((ext_vector_type(8)));   // 8 x bf16 (MFMA A/B frag)
typedef float  v4f __attribute__((ext_vector_type(4)));   // MFMA C/D frag

// bf16 helpers (RNE)
__device__ __forceinline__ uint32 f2bf(float f) {
    uint32 u = __float_as_uint(f);
    return (u + 0x7FFFu + ((u >> 16) & 1u)) >> 16;
}
__device__ __forceinline__ float bfl(uint32 u) { return __uint_as_float(u << 16); }
__device__ __forceinline__ float bfh(uint32 u) { return __uint_as_float(u & 0xFFFF0000u); }

// ---------------- CSR build: phase A — partition edges by dst group ----------------
// One sequential pass. Per block: wave-level group histogram via ballot,
// 8 global atomics reserve contiguous space per group, pairs written in
// ~2KB contiguous segments (merge perfectly in L2). Also counts cnt[d].

__global__ __launch_bounds__(256)
void partition_kernel(const int* __restrict__ src, const int* __restrict__ dst,
                      int* __restrict__ cnt, int* __restrict__ gcnt,
                      int2* __restrict__ staged) {
    __shared__ int lhist[NGRP];
    __shared__ int lbase[NGRP];
    __shared__ int lcur[NGRP];
    const int tid  = threadIdx.x;
    const int lane = tid & 63;
    const int e0   = blockIdx.x * EPB;

    if (tid < NGRP) lhist[tid] = 0;
    __syncthreads();

    int mys[EPT], myd[EPT], myg[EPT];
    int c[NGRP];
    #pragma unroll
    for (int g = 0; g < NGRP; ++g) c[g] = 0;

    #pragma unroll
    for (int i = 0; i < EPT; ++i) {
        int e = e0 + i * PART_T + tid;
        bool val = (e < N_EDGES);
        int d = 0, s = 0, g = -1;
        if (val) {
            d = dst[e];
            s = src[e];
            g = d / GDIV;
            atomicAdd(&cnt[d], 1);          // folded count pass
        }
        mys[i] = s; myd[i] = d; myg[i] = g;
        #pragma unroll
        for (int gg = 0; gg < NGRP; ++gg) c[gg] += (g == gg) ? 1 : 0;
    }

    // wave totals per group (all lanes end with the wave sum)
    #pragma unroll
    for (int gg = 0; gg < NGRP; ++gg) {
        #pragma unroll
        for (int m = 1; m < 64; m <<= 1) c[gg] += __shfl_xor(c[gg], m, 64);
    }
    if (lane == 0) {
        #pragma unroll
        for (int gg = 0; gg < NGRP; ++gg) atomicAdd(&lhist[gg], c[gg]);
    }
    __syncthreads();
    if (tid < NGRP) {
        lbase[tid] = atomicAdd(&gcnt[tid], lhist[tid]);   // 8 global atomics / block
        lcur[tid]  = 0;
    }
    __syncthreads();

    // per-wave sub-base within the block's reservation
    int wb[NGRP];
    if (lane == 0) {
        #pragma unroll
        for (int gg = 0; gg < NGRP; ++gg)
            wb[gg] = lbase[gg] + atomicAdd(&lcur[gg], c[gg]);
    }
    #pragma unroll
    for (int gg = 0; gg < NGRP; ++gg) wb[gg] = __shfl(wb[gg], 0, 64);

    // per-lane ranks via ballot, then write (s,d) pairs
    int cur[NGRP];
    #pragma unroll
    for (int gg = 0; gg < NGRP; ++gg) cur[gg] = 0;
    const unsigned long long lt = (1ull << lane) - 1ull;

    #pragma unroll
    for (int i = 0; i < EPT; ++i) {
        int g = myg[i];
        #pragma unroll
        for (int gg = 0; gg < NGRP; ++gg) {
            unsigned long long mask = __ballot(g == gg);
            if (g == gg) {
                int rank = cur[gg] + __popcll(mask & lt);
                staged[(size_t)gg * GCAP + wb[gg] + rank] = make_int2(mys[i], myd[i]);
            }
            cur[gg] += __popcll(mask);
        }
    }
}

// ---------------- CSR build: phase B — scatter within XCD-local window ----------------
// Group g's blocks read ONLY their staged slice (sequential) and write col
// inside an 800KB window; L2 working set ~2.5MB per XCD, no stream thrash.

__global__ __launch_bounds__(256)
void scatter_kernel(const int2* __restrict__ staged, const int* __restrict__ gcnt,
                    const int* __restrict__ row_ptr, int* __restrict__ fillc,
                    int* __restrict__ col) {
    const int g      = blockIdx.x & 7;
    const int bi     = blockIdx.x >> 3;
    const int stride = (gridDim.x >> 3) * 256;
    const int n      = gcnt[g];
    const int2* sp   = staged + (size_t)g * GCAP;
    for (int i = bi * 256 + threadIdx.x; i < n; i += stride) {
        int2 sd = sp[i];
        int p = row_ptr[sd.y] + atomicAdd(&fillc[sd.y], 1);
        col[p] = sd.x;
    }
}

// ---------------- scans ----------------

__global__ void scan1_kernel(const int* __restrict__ cnt, int* __restrict__ blk_sums) {
    __shared__ int red[1024];
    int t = threadIdx.x;
    int i = blockIdx.x * 1024 + t;
    red[t] = (i < N_NODES) ? cnt[i] : 0;
    __syncthreads();
    #pragma unroll
    for (int off = 512; off > 0; off >>= 1) {
        if (t < off) red[t] += red[t + off];
        __syncthreads();
    }
    if (t == 0) blk_sums[blockIdx.x] = red[0];
}

__global__ void scan2_kernel(int* __restrict__ blk_sums, int* __restrict__ row_ptr) {
    __shared__ int s[128];
    int t = threadIdx.x;
    int v = (t < SCAN_B) ? blk_sums[t] : 0;
    s[t] = v;
    __syncthreads();
    #pragma unroll
    for (int off = 1; off < 128; off <<= 1) {
        int add = (t >= off) ? s[t - off] : 0;
        __syncthreads();
        s[t] += add;
        __syncthreads();
    }
    if (t < SCAN_B) blk_sums[t] = s[t] - v;     // exclusive offset
    if (t == SCAN_B - 1) row_ptr[N_NODES] = s[t];
}

__global__ void scan3_kernel(const int* __restrict__ cnt, const int* __restrict__ blk_offs,
                             int* __restrict__ row_ptr, float* __restrict__ rdeg) {
    __shared__ int s[1024];
    int t = threadIdx.x;
    int i = blockIdx.x * 1024 + t;
    int c = (i < N_NODES) ? cnt[i] : 0;
    s[t] = c;
    __syncthreads();
    #pragma unroll
    for (int off = 1; off < 1024; off <<= 1) {
        int add = (t >= off) ? s[t - off] : 0;
        __syncthreads();
        s[t] += add;
        __syncthreads();
    }
    if (i < N_NODES) {
        row_ptr[i] = s[t] - c + blk_offs[blockIdx.x];
        rdeg[i] = 1.0f / (float)max(c, 1);
    }
}

// ---------------- weight pre-pack: fp32 Wn/Ws -> bf16 MFMA A-frags ----------------

__global__ void pack_w_kernel(const float* __restrict__ Wn, const float* __restrict__ Ws,
                              int nout, unsigned short* __restrict__ wfrag) {
    int tile = blockIdx.x;           // mt*8 + kt
    int kt   = tile & 7;
    int mt   = tile >> 3;
    int lane = threadIdx.x;          // 64
    int quad = lane >> 4;
    int m    = mt * 16 + (lane & 15);
    uint32 packed[4];
    #pragma unroll
    for (int jj = 0; jj < 4; ++jj) {
        uint32 lo = 0, hi = 0;
        #pragma unroll
        for (int b = 0; b < 2; ++b) {
            int j = jj * 2 + b;
            int k = kt * 32 + quad * 8 + j;
            float w = 0.f;
            if (m < nout) w = (k < F) ? Wn[(size_t)k * nout + m] : Ws[(size_t)(k - F) * nout + m];
            if (b == 0) lo = f2bf(w); else hi = f2bf(w);
        }
        packed[jj] = lo | (hi << 16);
    }
    uint4 o = make_uint4(packed[0], packed[1], packed[2], packed[3]);
    *(uint4*)(wfrag + ((size_t)tile * 64 + lane) * 8) = o;
}

// single-W pack (K=128, 4 k-tiles): tile = mt*4 + kt
__global__ void pack_w_single_kernel(const float* __restrict__ W, int nout,
                                     unsigned short* __restrict__ wfrag) {
    int tile = blockIdx.x;
    int kt   = tile & 3;
    int mt   = tile >> 2;
    int lane = threadIdx.x;
    int quad = lane >> 4;
    int m    = mt * 16 + (lane & 15);
    uint32 packed[4];
    #pragma unroll
    for (int jj = 0; jj < 4; ++jj) {
        uint32 lo = 0, hi = 0;
        #pragma unroll
        for (int b = 0; b < 2; ++b) {
            int k = kt * 32 + quad * 8 + jj * 2 + b;
            float w = (m < nout) ? W[(size_t)k * nout + m] : 0.f;
            if (b == 0) lo = f2bf(w); else hi = f2bf(w);
        }
        packed[jj] = lo | (hi << 16);
    }
    uint4 o = make_uint4(packed[0], packed[1], packed[2], packed[3]);
    *(uint4*)(wfrag + ((size_t)tile * 64 + lane) * 8) = o;
}

// ---------------- embedding gather: fp32 embed -> bf16 h ----------------

__global__ void gather_embed_kernel(const float* __restrict__ embed,
                                    const int* __restrict__ idx,
                                    unsigned short* __restrict__ h) {
    int i = blockIdx.x * blockDim.x + threadIdx.x;
    const int TOTAL = N_NODES * (F / 4);
    if (i < TOTAL) {
        int node = i >> 5;
        int c4 = i & 31;
        float4 v = ((const float4*)(embed + (size_t)idx[node] * F))[c4];
        uint2 o;
        o.x = f2bf(v.x) | (f2bf(v.y) << 16);
        o.y = f2bf(v.z) | (f2bf(v.w) << 16);
        ((uint2*)(h + (size_t)node * F))[c4] = o;
    }
}

// ---------------- pull aggregation (bf16 h -> bf16 mean, fp32 accum) ----------------
// one wave per node; 4 sub-groups x 16 lanes; each sub-group loads a FULL
// 256B neighbor row as uint4 (16B/lane) -> 4 edges per iter. col prefetched
// one iter ahead. Epilogue: shfl_xor(16,32) merges the 4 sub-group partials.

__global__ void aggregate_kernel(const unsigned short* __restrict__ h,
                                 const int* __restrict__ row_ptr,
                                 const int* __restrict__ col,
                                 const float* __restrict__ rdeg,
                                 unsigned short* __restrict__ mean) {
    const int wave = threadIdx.x >> 6;
    const int lane = threadIdx.x & 63;
    const int sub  = lane >> 4;          // which of 4 edges per iter
    const int li   = lane & 15;          // 16B slot within the row
    const int v    = blockIdx.x * 4 + wave;
    if (v >= N_NODES) return;

    const uint4* hp4 = (const uint4*)h;  // 16 uint4 per 256B row
    const int beg = row_ptr[v], end = row_ptr[v + 1];

    float a0 = 0.f, a1 = 0.f, a2 = 0.f, a3 = 0.f;
    float a4 = 0.f, a5 = 0.f, a6 = 0.f, a7 = 0.f;

    int p = beg;
    int u = col[min(p + sub, N_EDGES - 1)];   // prefetch (clamped, safe)
    #pragma unroll 2
    for (; p + 4 <= end; p += 4) {
        int un = col[min(p + 4 + sub, N_EDGES - 1)];
        uint4 x = hp4[(size_t)u * 16 + li];
        a0 += bfl(x.x); a1 += bfh(x.x);
        a2 += bfl(x.y); a3 += bfh(x.y);
        a4 += bfl(x.z); a5 += bfh(x.z);
        a6 += bfl(x.w); a7 += bfh(x.w);
        u = un;
    }
    if (p + sub < end) {                      // tail (u already prefetched)
        uint4 x = hp4[(size_t)u * 16 + li];
        a0 += bfl(x.x); a1 += bfh(x.x);
        a2 += bfl(x.y); a3 += bfh(x.y);
        a4 += bfl(x.z); a5 += bfh(x.z);
        a6 += bfl(x.w); a7 += bfh(x.w);
    }

    #pragma unroll
    for (int m = 16; m <= 32; m <<= 1) {
        a0 += __shfl_xor(a0, m, 64);
        a1 += __shfl_xor(a1, m, 64);
        a2 += __shfl_xor(a2, m, 64);
        a3 += __shfl_xor(a3, m, 64);
        a4 += __shfl_xor(a4, m, 64);
        a5 += __shfl_xor(a5, m, 64);
        a6 += __shfl_xor(a6, m, 64);
        a7 += __shfl_xor(a7, m, 64);
    }

    if (sub == 0) {
        const float r = rdeg[v];
        uint4 o;
        o.x = f2bf(a0 * r) | (f2bf(a1 * r) << 16);
        o.y = f2bf(a2 * r) | (f2bf(a3 * r) << 16);
        o.z = f2bf(a4 * r) | (f2bf(a5 * r) << 16);
        o.w = f2bf(a6 * r) | (f2bf(a7 * r) << 16);
        ((uint4*)mean)[(size_t)v * 16 + li] = o;
    }
}

// 48-wide aggregation over 128B rows (layer 2, post-transform).
// 8 sub-groups x 8 lanes; each sub-group loads a full 128B row (uint4/lane).

__global__ void aggregate48_kernel(const unsigned short* __restrict__ hn,
                                   const int* __restrict__ row_ptr,
                                   const int* __restrict__ col,
                                   const float* __restrict__ rdeg,
                                   unsigned short* __restrict__ mean) {
    const int wave = threadIdx.x >> 6;
    const int lane = threadIdx.x & 63;
    const int sub  = lane >> 3;          // which of 8 edges per iter
    const int li   = lane & 7;           // 16B slot within the 128B row
    const int v    = blockIdx.x * 4 + wave;
    if (v >= N_NODES) return;

    const uint4* hp4 = (const uint4*)hn; // 8 uint4 per 128B row
    const int beg = row_ptr[v], end = row_ptr[v + 1];

    float a0 = 0.f, a1 = 0.f, a2 = 0.f, a3 = 0.f;
    float a4 = 0.f, a5 = 0.f, a6 = 0.f, a7 = 0.f;

    int p = beg;
    int u = col[min(p + sub, N_EDGES - 1)];
    #pragma unroll 2
    for (; p + 8 <= end; p += 8) {
        int un = col[min(p + 8 + sub, N_EDGES - 1)];
        uint4 x = hp4[(size_t)u * 8 + li];
        a0 += bfl(x.x); a1 += bfh(x.x);
        a2 += bfl(x.y); a3 += bfh(x.y);
        a4 += bfl(x.z); a5 += bfh(x.z);
        a6 += bfl(x.w); a7 += bfh(x.w);
        u = un;
    }
    if (p + sub < end) {
        uint4 x = hp4[(size_t)u * 8 + li];
        a0 += bfl(x.x); a1 += bfh(x.x);
        a2 += bfl(x.y); a3 += bfh(x.y);
        a4 += bfl(x.z); a5 += bfh(x.z);
        a6 += bfl(x.w); a7 += bfh(x.w);
    }

    #pragma unroll
    for (int m = 8; m <= 32; m <<= 1) {
        a0 += __shfl_xor(a0, m, 64);
        a1 += __shfl_xor(a1, m, 64);
        a2 += __shfl_xor(a2, m, 64);
        a3 += __shfl_xor(a3, m, 64);
        a4 += __shfl_xor(a4, m, 64);
        a5 += __shfl_xor(a5, m, 64);
        a6 += __shfl_xor(a6, m, 64);
        a7 += __shfl_xor(a7, m, 64);
    }

    if (sub == 0) {
        const float r = rdeg[v];
        uint4 o;
        o.x = f2bf(a0 * r) | (f2bf(a1 * r) << 16);
        o.y = f2bf(a2 * r) | (f2bf(a3 * r) << 16);
        o.z = f2bf(a4 * r) | (f2bf(a5 * r) << 16);
        o.w = f2bf(a6 * r) | (f2bf(a7 * r) << 16);
        ((uint4*)mean)[(size_t)v * 8 + li] = o;
    }
}

// ---------------- MFMA GEMM: out = [mean|h] @ Wcat + b (+relu), bf16 out ----------------

template<int MT, bool RELU>
__global__ __launch_bounds__(256)
void mfma_gemm_kernel(const unsigned short* __restrict__ meanb,
                      const unsigned short* __restrict__ h,
                      const unsigned short* __restrict__ wfrag,
                      const float* __restrict__ bias,
                      unsigned short* __restrict__ out) {
    const int lane = threadIdx.x & 63;
    const int wave = threadIdx.x >> 6;
    const int quad = lane >> 4;
    const int nn   = lane & 15;
    const int base = blockIdx.x * 128 + wave * 32;

    const int n0 = base + nn;
    const int n1 = base + 16 + nn;
    const size_t r0 = (size_t)min(n0, N_NODES - 1) * F;
    const size_t r1 = (size_t)min(n1, N_NODES - 1) * F;

    v4f acc[MT][2];
    #pragma unroll
    for (int mt = 0; mt < MT; ++mt) { acc[mt][0] = (v4f)0.f; acc[mt][1] = (v4f)0.f; }

    #pragma unroll
    for (int kt = 0; kt < 8; ++kt) {
        const unsigned short* B = (kt < 4) ? meanb : h;
        const int koff = (kt & 3) * 32 + quad * 8;
        v8s b0 = *(const v8s*)(B + r0 + koff);
        v8s b1 = *(const v8s*)(B + r1 + koff);
        #pragma unroll
        for (int mt = 0; mt < MT; ++mt) {
            v8s a = *(const v8s*)(wfrag + ((size_t)(mt * 8 + kt) * 64 + lane) * 8);
            acc[mt][0] = __builtin_amdgcn_mfma_f32_16x16x32_bf16(a, b0, acc[mt][0], 0, 0, 0);
            acc[mt][1] = __builtin_amdgcn_mfma_f32_16x16x32_bf16(a, b1, acc[mt][1], 0, 0, 0);
        }
    }

    #pragma unroll
    for (int mt = 0; mt < MT; ++mt) {
        const int m0 = mt * 16 + quad * 4;
        #pragma unroll
        for (int nt = 0; nt < 2; ++nt) {
            const int node = base + nt * 16 + nn;
            if (node >= N_NODES) continue;
            v4f a = acc[mt][nt];
            const float4 bb = *(const float4*)(bias + m0);
            float x0 = a[0] + bb.x, x1 = a[1] + bb.y, x2 = a[2] + bb.z, x3 = a[3] + bb.w;
            if (RELU) {
                x0 = fmaxf(x0, 0.f); x1 = fmaxf(x1, 0.f);
                x2 = fmaxf(x2, 0.f); x3 = fmaxf(x3, 0.f);
            }
            uint2 o;
            o.x = f2bf(x0) | (f2bf(x1) << 16);
            o.y = f2bf(x2) | (f2bf(x3) << 16);
            *(uint2*)(out + (size_t)node * F + m0) = o;
        }
    }
}

// ---------------- layer-2: hn2 = h @ Wn2 (bf16 out, row stride 64) ----------------
// mean is linear: mean(h) @ Wn2 == mean(h @ Wn2). Transform first so the
// per-edge gather reads 128B rows instead of 256B.

__global__ __launch_bounds__(256)
void gemm_hn2_kernel(const unsigned short* __restrict__ h,
                     const unsigned short* __restrict__ wfrag,
                     unsigned short* __restrict__ hn2) {
    const int lane = threadIdx.x & 63;
    const int wave = threadIdx.x >> 6;
    const int quad = lane >> 4;
    const int nn   = lane & 15;
    const int base = blockIdx.x * 128 + wave * 32;

    const int n0 = base + nn;
    const int n1 = base + 16 + nn;
    const size_t r0 = (size_t)min(n0, N_NODES - 1) * F;
    const size_t r1 = (size_t)min(n1, N_NODES - 1) * F;

    v4f acc[3][2];
    #pragma unroll
    for (int mt = 0; mt < 3; ++mt) { acc[mt][0] = (v4f)0.f; acc[mt][1] = (v4f)0.f; }

    #pragma unroll
    for (int kt = 0; kt < 4; ++kt) {
        const int koff = kt * 32 + quad * 8;
        v8s b0 = *(const v8s*)(h + r0 + koff);
        v8s b1 = *(const v8s*)(h + r1 + koff);
        #pragma unroll
        for (int mt = 0; mt < 3; ++mt) {
            v8s a = *(const v8s*)(wfrag + ((size_t)(mt * 4 + kt) * 64 + lane) * 8);
            acc[mt][0] = __builtin_amdgcn_mfma_f32_16x16x32_bf16(a, b0, acc[mt][0], 0, 0, 0);
            acc[mt][1] = __builtin_amdgcn_mfma_f32_16x16x32_bf16(a, b1, acc[mt][1], 0, 0, 0);
        }
    }

    #pragma unroll
    for (int mt = 0; mt < 3; ++mt) {
        const int m0 = mt * 16 + quad * 4;   // 0..47
        #pragma unroll
        for (int nt = 0; nt < 2; ++nt) {
            const int node = base + nt * 16 + nn;
            if (node >= N_NODES) continue;
            v4f a = acc[mt][nt];
            uint2 o;
            o.x = f2bf(a[0]) | (f2bf(a[1]) << 16);
            o.y = f2bf(a[2]) | (f2bf(a[3]) << 16);
            *(uint2*)(hn2 + (size_t)node * 64 + m0) = o;
        }
    }
}

// ---------------- layer-2 final: out = mean2 + h @ Ws2 + b2 (fp32 out) ----------------

__global__ __launch_bounds__(256)
void final_kernel(const unsigned short* __restrict__ h,
                  const unsigned short* __restrict__ mean2,
                  const unsigned short* __restrict__ wfrag,
                  const float* __restrict__ bias,
                  float* __restrict__ out) {
    const int lane = threadIdx.x & 63;
    const int wave = threadIdx.x >> 6;
    const int quad = lane >> 4;
    const int nn   = lane & 15;
    const int base = blockIdx.x * 128 + wave * 32;

    const int n0 = base + nn;
    const int n1 = base + 16 + nn;
    const size_t r0 = (size_t)min(n0, N_NODES - 1) * F;
    const size_t r1 = (size_t)min(n1, N_NODES - 1) * F;

    v4f acc[3][2];
    #pragma unroll
    for (int mt = 0; mt < 3; ++mt) { acc[mt][0] = (v4f)0.f; acc[mt][1] = (v4f)0.f; }

    #pragma unroll
    for (int kt = 0; kt < 4; ++kt) {
        const int koff = kt * 32 + quad * 8;
        v8s b0 = *(const v8s*)(h + r0 + koff);
        v8s b1 = *(const v8s*)(h + r1 + koff);
        #pragma unroll
        for (int mt = 0; mt < 3; ++mt) {
            v8s a = *(const v8s*)(wfrag + ((size_t)(mt * 4 + kt) * 64 + lane) * 8);
            acc[mt][0] = __builtin_amdgcn_mfma_f32_16x16x32_bf16(a, b0, acc[mt][0], 0, 0, 0);
            acc[mt][1] = __builtin_amdgcn_mfma_f32_16x16x32_bf16(a, b1, acc[mt][1], 0, 0, 0);
        }
    }

    #pragma unroll
    for (int mt = 0; mt < 3; ++mt) {
        const int m0 = mt * 16 + quad * 4;   // 0..47, multiple of 4
        #pragma unroll
        for (int nt = 0; nt < 2; ++nt) {
            const int node = base + nt * 16 + nn;
            if (node >= N_NODES) continue;
            v4f a = acc[mt][nt];
            uint2 mv = *(const uint2*)(mean2 + (size_t)node * 64 + m0);
            float mf[4] = { bfl(mv.x), bfh(mv.x), bfl(mv.y), bfh(mv.y) };
            #pragma unroll
            for (int r = 0; r < 4; ++r) {
                int m = m0 + r;
                if (m < N_CLASSES)
                    out[(size_t)node * N_CLASSES + m] = a[r] + bias[m] + mf[r];
            }
        }
    }
}

// ---------------- launch ----------------

extern "C" void kernel_launch(void* const* d_in, const int* in_sizes, int n_in,
                              void* d_out, int out_size, void* d_ws, size_t ws_size,
                              hipStream_t stream) {
    const float* embed = (const float*)d_in[0];
    const float* Ws0   = (const float*)d_in[1];
    const float* Wn0   = (const float*)d_in[2];
    const float* b0    = (const float*)d_in[3];
    const float* Ws1   = (const float*)d_in[4];
    const float* Wn1   = (const float*)d_in[5];
    const float* b1    = (const float*)d_in[6];
    const float* Ws2   = (const float*)d_in[7];
    const float* Wn2   = (const float*)d_in[8];
    const float* b2    = (const float*)d_in[9];
    const int* input_nodes = (const int*)d_in[10];
    const int* src     = (const int*)d_in[11];
    const int* dst     = (const int*)d_in[12];
    float* out = (float*)d_out;

    char* ws = (char*)d_ws;
    size_t off = 0;
    auto alloc = [&](size_t bytes) -> void* {
        void* p = ws + off;
        off += (bytes + 255) & ~(size_t)255;
        return p;
    };
    int*            cnt      = (int*)           alloc(sizeof(int)   * N_NODES);
    int*            fillc    = (int*)           alloc(sizeof(int)   * N_NODES);
    int*            row_ptr  = (int*)           alloc(sizeof(int)   * (N_NODES + 1));
    float*          rdeg     = (float*)         alloc(sizeof(float) * N_NODES);
    int*            col      = (int*)           alloc(sizeof(int)   * N_EDGES);
    int*            blk_sums = (int*)           alloc(sizeof(int)   * 128);
    int*            gcnt     = (int*)           alloc(sizeof(int)   * NGRP);
    unsigned short* h_a      = (unsigned short*)alloc(2 * (size_t)N_NODES * F);
    unsigned short* h_b      = (unsigned short*)alloc(2 * (size_t)N_NODES * F);
    unsigned short* meanb    = (unsigned short*)alloc(2 * (size_t)N_NODES * F);
    unsigned short* wf0      = (unsigned short*)alloc(2 * 64 * 512);
    unsigned short* wf1      = (unsigned short*)alloc(2 * 64 * 512);
    unsigned short* wf2n     = (unsigned short*)alloc(2 * 12 * 512);
    unsigned short* wf2s     = (unsigned short*)alloc(2 * 12 * 512);
    (void)ws_size; (void)n_in; (void)in_sizes; (void)out_size;

    // staged edge pairs alias meanb: staged is dead before the first
    // aggregate writes meanb (same stream, serialized). 8*220000*8B = 14MB < 25.6MB.
    int2* staged = (int2*)meanb;

    hipMemsetAsync(cnt,   0, sizeof(int) * N_NODES, stream);
    hipMemsetAsync(fillc, 0, sizeof(int) * N_NODES, stream);
    hipMemsetAsync(gcnt,  0, sizeof(int) * NGRP,    stream);

    partition_kernel<<<PART_B, PART_T, 0, stream>>>(src, dst, cnt, gcnt, staged);
    scan1_kernel<<<SCAN_B, 1024, 0, stream>>>(cnt, blk_sums);
    scan2_kernel<<<1, 128, 0, stream>>>(blk_sums, row_ptr);
    scan3_kernel<<<SCAN_B, 1024, 0, stream>>>(cnt, blk_sums, row_ptr, rdeg);
    scatter_kernel<<<4096, 256, 0, stream>>>(staged, gcnt, row_ptr, fillc, col);

    pack_w_kernel<<<64, 64, 0, stream>>>(Wn0, Ws0, F, wf0);
    pack_w_kernel<<<64, 64, 0, stream>>>(Wn1, Ws1, F, wf1);
    pack_w_single_kernel<<<12, 64, 0, stream>>>(Wn2, N_CLASSES, wf2n);
    pack_w_single_kernel<<<12, 64, 0, stream>>>(Ws2, N_CLASSES, wf2s);

    gather_embed_kernel<<<(N_NODES * (F / 4) + 255) / 256, 256, 0, stream>>>(embed, input_nodes, h_a);

    const int AGG_B  = (N_NODES + 3) / 4;
    const int GEMM_B = (N_NODES + 127) / 128;

    // layer 0: h_a -> h_b
    aggregate_kernel<<<AGG_B, 256, 0, stream>>>(h_a, row_ptr, col, rdeg, meanb);
    mfma_gemm_kernel<8, true><<<GEMM_B, 256, 0, stream>>>(meanb, h_a, wf0, b0, h_b);
    // layer 1: h_b -> h_a
    aggregate_kernel<<<AGG_B, 256, 0, stream>>>(h_b, row_ptr, col, rdeg, meanb);
    mfma_gemm_kernel<8, true><<<GEMM_B, 256, 0, stream>>>(meanb, h_b, wf1, b1, h_a);
    // layer 2 (transform-first): hn2 = h_a @ Wn2 (rows padded to 64, reuse h_b);
    // mean2 = mean-aggregate(hn2) (reuse meanb); out = mean2 + h_a @ Ws2 + b2
    gemm_hn2_kernel<<<GEMM_B, 256, 0, stream>>>(h_a, wf2n, h_b);
    aggregate48_kernel<<<AGG_B, 256, 0, stream>>>(h_b, row_ptr, col, rdeg, meanb);
    final_kernel<<<GEMM_B, 256, 0, stream>>>(h_a, meanb, wf2s, b2, out);
}

// Round 5
// 519.693 us; speedup vs baseline: 1.0925x; 1.0925x over previous
//
#include <hip/hip_runtime.h>

#define N_NODES   100000
#define N_EDGES   1600000
#define F         128
#define N_CLASSES 47

#define NGRP      8
#define GDIV      12500          // nodes per XCD group
#define GCAP      220000         // staging capacity per group (expect ~200K)
#define CAP       64             // col slab capacity per node (Poisson(16): P(>64)~1e-20)
#define EPT       2              // edges per thread in partition
#define PART_T    256
#define EPB       (PART_T * EPT) // 512 edges per block
#define PART_B    ((N_EDGES + EPB - 1) / EPB)

typedef unsigned int uint32;

typedef short  v8s __attribute__((ext_vector_type(8)));   // 8 x bf16 (MFMA A/B frag)
typedef float  v4f __attribute__((ext_vector_type(4)));   // MFMA C/D frag

// bf16 helpers (RNE)
__device__ __forceinline__ uint32 f2bf(float f) {
    uint32 u = __float_as_uint(f);
    return (u + 0x7FFFu + ((u >> 16) & 1u)) >> 16;
}
__device__ __forceinline__ float bfl(uint32 u) { return __uint_as_float(u << 16); }
__device__ __forceinline__ float bfh(uint32 u) { return __uint_as_float(u & 0xFFFF0000u); }

// ---------------- phase A: partition edges by dst group (no per-edge atomics) ----------------
// Rank-in-wave comes from the ballot pass itself (popcll of full mask is
// lane-uniform -> wave totals free); per-wave bases via small LDS table;
// 8 global atomics per block reserve contiguous staged space.

__global__ __launch_bounds__(256)
void partition_kernel(const int* __restrict__ src, const int* __restrict__ dst,
                      int* __restrict__ gcnt, int2* __restrict__ staged) {
    __shared__ int lw[4][NGRP];
    __shared__ int gbase[NGRP];
    const int tid  = threadIdx.x;
    const int lane = tid & 63;
    const int w    = tid >> 6;
    const int e0   = blockIdx.x * EPB;
    const unsigned long long lt = (1ull << lane) - 1ull;

    int mys[EPT], myd[EPT], myg[EPT], myrank[EPT];
    int wavec[NGRP];
    #pragma unroll
    for (int g = 0; g < NGRP; ++g) wavec[g] = 0;

    #pragma unroll
    for (int i = 0; i < EPT; ++i) {
        int e = e0 + i * PART_T + tid;
        bool val = (e < N_EDGES);
        int d = val ? dst[e] : 0;
        int s = val ? src[e] : 0;
        int g = val ? (d / GDIV) : -1;
        mys[i] = s; myd[i] = d; myg[i] = g; myrank[i] = 0;
        #pragma unroll
        for (int gg = 0; gg < NGRP; ++gg) {
            unsigned long long mask = __ballot(g == gg);
            if (g == gg) myrank[i] = wavec[gg] + __popcll(mask & lt);
            wavec[gg] += __popcll(mask);      // lane-uniform
        }
    }

    #pragma unroll
    for (int gg = 0; gg < NGRP; ++gg) if (lane == gg) lw[w][gg] = wavec[gg];
    __syncthreads();
    if (tid < NGRP) {
        int tot = lw[0][tid] + lw[1][tid] + lw[2][tid] + lw[3][tid];
        gbase[tid] = atomicAdd(&gcnt[tid], tot);     // 8 global atomics / block
    }
    __syncthreads();

    int wb[NGRP];
    #pragma unroll
    for (int gg = 0; gg < NGRP; ++gg) {
        int b = gbase[gg];
        if (w > 0) b += lw[0][gg];
        if (w > 1) b += lw[1][gg];
        if (w > 2) b += lw[2][gg];
        wb[gg] = b;
    }

    #pragma unroll
    for (int i = 0; i < EPT; ++i) {
        int g = myg[i];
        if (g >= 0) {
            int base = 0;
            #pragma unroll
            for (int gg = 0; gg < NGRP; ++gg)
                base = (g == gg) ? (gg * GCAP + wb[gg]) : base;   // static-indexed select
            staged[(size_t)base + myrank[i]] = make_int2(mys[i], myd[i]);
        }
    }
}

// ---------------- phase B: scatter into fixed-capacity slabs (single atomic pass) ----------------
// Group g's blocks read only their staged slice (sequential); fillc window
// 50KB and col window stay XCD-local. No row_ptr: slab layout.

__global__ __launch_bounds__(256)
void scatter_kernel(const int2* __restrict__ staged, const int* __restrict__ gcnt,
                    int* __restrict__ fillc, int* __restrict__ col) {
    const int g      = blockIdx.x & 7;
    const int bi     = blockIdx.x >> 3;
    const int stride = (gridDim.x >> 3) * 256;
    const int n      = gcnt[g];
    const int2* sp   = staged + (size_t)g * GCAP;
    for (int i = bi * 256 + threadIdx.x; i < n; i += stride) {
        int2 sd = sp[i];
        int p = atomicAdd(&fillc[sd.y], 1);
        if (p < CAP) col[(size_t)sd.y * CAP + p] = sd.x;
    }
}

// deg -> reciprocal degree
__global__ void rdeg_kernel(const int* __restrict__ deg, float* __restrict__ rdeg) {
    int i = blockIdx.x * blockDim.x + threadIdx.x;
    if (i < N_NODES) rdeg[i] = 1.0f / (float)max(deg[i], 1);
}

// ---------------- weight pre-pack: fp32 Wn/Ws -> bf16 MFMA A-frags ----------------

__global__ void pack_w_kernel(const float* __restrict__ Wn, const float* __restrict__ Ws,
                              int nout, unsigned short* __restrict__ wfrag) {
    int tile = blockIdx.x;           // mt*8 + kt
    int kt   = tile & 7;
    int mt   = tile >> 3;
    int lane = threadIdx.x;          // 64
    int quad = lane >> 4;
    int m    = mt * 16 + (lane & 15);
    uint32 packed[4];
    #pragma unroll
    for (int jj = 0; jj < 4; ++jj) {
        uint32 lo = 0, hi = 0;
        #pragma unroll
        for (int b = 0; b < 2; ++b) {
            int j = jj * 2 + b;
            int k = kt * 32 + quad * 8 + j;
            float w = 0.f;
            if (m < nout) w = (k < F) ? Wn[(size_t)k * nout + m] : Ws[(size_t)(k - F) * nout + m];
            if (b == 0) lo = f2bf(w); else hi = f2bf(w);
        }
        packed[jj] = lo | (hi << 16);
    }
    uint4 o = make_uint4(packed[0], packed[1], packed[2], packed[3]);
    *(uint4*)(wfrag + ((size_t)tile * 64 + lane) * 8) = o;
}

// single-W pack (K=128, 4 k-tiles): tile = mt*4 + kt
__global__ void pack_w_single_kernel(const float* __restrict__ W, int nout,
                                     unsigned short* __restrict__ wfrag) {
    int tile = blockIdx.x;
    int kt   = tile & 3;
    int mt   = tile >> 2;
    int lane = threadIdx.x;
    int quad = lane >> 4;
    int m    = mt * 16 + (lane & 15);
    uint32 packed[4];
    #pragma unroll
    for (int jj = 0; jj < 4; ++jj) {
        uint32 lo = 0, hi = 0;
        #pragma unroll
        for (int b = 0; b < 2; ++b) {
            int k = kt * 32 + quad * 8 + jj * 2 + b;
            float w = (m < nout) ? W[(size_t)k * nout + m] : 0.f;
            if (b == 0) lo = f2bf(w); else hi = f2bf(w);
        }
        packed[jj] = lo | (hi << 16);
    }
    uint4 o = make_uint4(packed[0], packed[1], packed[2], packed[3]);
    *(uint4*)(wfrag + ((size_t)tile * 64 + lane) * 8) = o;
}

// ---------------- embedding gather: fp32 embed -> bf16 h ----------------

__global__ void gather_embed_kernel(const float* __restrict__ embed,
                                    const int* __restrict__ idx,
                                    unsigned short* __restrict__ h) {
    int i = blockIdx.x * blockDim.x + threadIdx.x;
    const int TOTAL = N_NODES * (F / 4);
    if (i < TOTAL) {
        int node = i >> 5;
        int c4 = i & 31;
        float4 v = ((const float4*)(embed + (size_t)idx[node] * F))[c4];
        uint2 o;
        o.x = f2bf(v.x) | (f2bf(v.y) << 16);
        o.y = f2bf(v.z) | (f2bf(v.w) << 16);
        ((uint2*)(h + (size_t)node * F))[c4] = o;
    }
}

// ---------------- pull aggregation (bf16 h -> bf16 mean, fp32 accum) ----------------
// one wave per node; 4 sub-groups x 16 lanes; each sub-group loads a FULL
// 256B neighbor row as uint4 (16B/lane) -> 4 edges per iter. col slab is
// v*CAP .. v*CAP+deg. Prefetch index clamped to the initialized region.

__global__ void aggregate_kernel(const unsigned short* __restrict__ h,
                                 const int* __restrict__ deg,
                                 const int* __restrict__ col,
                                 const float* __restrict__ rdeg,
                                 unsigned short* __restrict__ mean) {
    const int wave = threadIdx.x >> 6;
    const int lane = threadIdx.x & 63;
    const int sub  = lane >> 4;          // which of 4 edges per iter
    const int li   = lane & 15;          // 16B slot within the row
    const int v    = blockIdx.x * 4 + wave;
    if (v >= N_NODES) return;

    const uint4* hp4 = (const uint4*)h;  // 16 uint4 per 256B row
    const int beg = v * CAP;
    const int end = beg + deg[v];
    const int dmax = max(end - 1, beg);  // clamp: padded slots are garbage

    float a0 = 0.f, a1 = 0.f, a2 = 0.f, a3 = 0.f;
    float a4 = 0.f, a5 = 0.f, a6 = 0.f, a7 = 0.f;

    int p = beg;
    int u = col[min(p + sub, dmax)];     // prefetch (clamped)
    #pragma unroll 2
    for (; p + 4 <= end; p += 4) {
        int un = col[min(p + 4 + sub, dmax)];
        uint4 x = hp4[(size_t)u * 16 + li];
        a0 += bfl(x.x); a1 += bfh(x.x);
        a2 += bfl(x.y); a3 += bfh(x.y);
        a4 += bfl(x.z); a5 += bfh(x.z);
        a6 += bfl(x.w); a7 += bfh(x.w);
        u = un;
    }
    if (p + sub < end) {                 // tail (u prefetched from valid slot)
        uint4 x = hp4[(size_t)u * 16 + li];
        a0 += bfl(x.x); a1 += bfh(x.x);
        a2 += bfl(x.y); a3 += bfh(x.y);
        a4 += bfl(x.z); a5 += bfh(x.z);
        a6 += bfl(x.w); a7 += bfh(x.w);
    }

    #pragma unroll
    for (int m = 16; m <= 32; m <<= 1) {
        a0 += __shfl_xor(a0, m, 64);
        a1 += __shfl_xor(a1, m, 64);
        a2 += __shfl_xor(a2, m, 64);
        a3 += __shfl_xor(a3, m, 64);
        a4 += __shfl_xor(a4, m, 64);
        a5 += __shfl_xor(a5, m, 64);
        a6 += __shfl_xor(a6, m, 64);
        a7 += __shfl_xor(a7, m, 64);
    }

    if (sub == 0) {
        const float r = rdeg[v];
        uint4 o;
        o.x = f2bf(a0 * r) | (f2bf(a1 * r) << 16);
        o.y = f2bf(a2 * r) | (f2bf(a3 * r) << 16);
        o.z = f2bf(a4 * r) | (f2bf(a5 * r) << 16);
        o.w = f2bf(a6 * r) | (f2bf(a7 * r) << 16);
        ((uint4*)mean)[(size_t)v * 16 + li] = o;
    }
}

// 48-wide aggregation over 128B rows (layer 2, post-transform).
// 8 sub-groups x 8 lanes; each sub-group loads a full 128B row (uint4/lane).

__global__ void aggregate48_kernel(const unsigned short* __restrict__ hn,
                                   const int* __restrict__ deg,
                                   const int* __restrict__ col,
                                   const float* __restrict__ rdeg,
                                   unsigned short* __restrict__ mean) {
    const int wave = threadIdx.x >> 6;
    const int lane = threadIdx.x & 63;
    const int sub  = lane >> 3;          // which of 8 edges per iter
    const int li   = lane & 7;           // 16B slot within the 128B row
    const int v    = blockIdx.x * 4 + wave;
    if (v >= N_NODES) return;

    const uint4* hp4 = (const uint4*)hn; // 8 uint4 per 128B row
    const int beg = v * CAP;
    const int end = beg + deg[v];
    const int dmax = max(end - 1, beg);

    float a0 = 0.f, a1 = 0.f, a2 = 0.f, a3 = 0.f;
    float a4 = 0.f, a5 = 0.f, a6 = 0.f, a7 = 0.f;

    int p = beg;
    int u = col[min(p + sub, dmax)];
    #pragma unroll 2
    for (; p + 8 <= end; p += 8) {
        int un = col[min(p + 8 + sub, dmax)];
        uint4 x = hp4[(size_t)u * 8 + li];
        a0 += bfl(x.x); a1 += bfh(x.x);
        a2 += bfl(x.y); a3 += bfh(x.y);
        a4 += bfl(x.z); a5 += bfh(x.z);
        a6 += bfl(x.w); a7 += bfh(x.w);
        u = un;
    }
    if (p + sub < end) {
        uint4 x = hp4[(size_t)u * 8 + li];
        a0 += bfl(x.x); a1 += bfh(x.x);
        a2 += bfl(x.y); a3 += bfh(x.y);
        a4 += bfl(x.z); a5 += bfh(x.z);
        a6 += bfl(x.w); a7 += bfh(x.w);
    }

    #pragma unroll
    for (int m = 8; m <= 32; m <<= 1) {
        a0 += __shfl_xor(a0, m, 64);
        a1 += __shfl_xor(a1, m, 64);
        a2 += __shfl_xor(a2, m, 64);
        a3 += __shfl_xor(a3, m, 64);
        a4 += __shfl_xor(a4, m, 64);
        a5 += __shfl_xor(a5, m, 64);
        a6 += __shfl_xor(a6, m, 64);
        a7 += __shfl_xor(a7, m, 64);
    }

    if (sub == 0) {
        const float r = rdeg[v];
        uint4 o;
        o.x = f2bf(a0 * r) | (f2bf(a1 * r) << 16);
        o.y = f2bf(a2 * r) | (f2bf(a3 * r) << 16);
        o.z = f2bf(a4 * r) | (f2bf(a5 * r) << 16);
        o.w = f2bf(a6 * r) | (f2bf(a7 * r) << 16);
        ((uint4*)mean)[(size_t)v * 8 + li] = o;
    }
}

// ---------------- MFMA GEMM: out = [mean|h] @ Wcat + b (+relu), bf16 out ----------------

template<int MT, bool RELU>
__global__ __launch_bounds__(256)
void mfma_gemm_kernel(const unsigned short* __restrict__ meanb,
                      const unsigned short* __restrict__ h,
                      const unsigned short* __restrict__ wfrag,
                      const float* __restrict__ bias,
                      unsigned short* __restrict__ out) {
    const int lane = threadIdx.x & 63;
    const int wave = threadIdx.x >> 6;
    const int quad = lane >> 4;
    const int nn   = lane & 15;
    const int base = blockIdx.x * 128 + wave * 32;

    const int n0 = base + nn;
    const int n1 = base + 16 + nn;
    const size_t r0 = (size_t)min(n0, N_NODES - 1) * F;
    const size_t r1 = (size_t)min(n1, N_NODES - 1) * F;

    v4f acc[MT][2];
    #pragma unroll
    for (int mt = 0; mt < MT; ++mt) { acc[mt][0] = (v4f)0.f; acc[mt][1] = (v4f)0.f; }

    #pragma unroll
    for (int kt = 0; kt < 8; ++kt) {
        const unsigned short* B = (kt < 4) ? meanb : h;
        const int koff = (kt & 3) * 32 + quad * 8;
        v8s b0 = *(const v8s*)(B + r0 + koff);
        v8s b1 = *(const v8s*)(B + r1 + koff);
        #pragma unroll
        for (int mt = 0; mt < MT; ++mt) {
            v8s a = *(const v8s*)(wfrag + ((size_t)(mt * 8 + kt) * 64 + lane) * 8);
            acc[mt][0] = __builtin_amdgcn_mfma_f32_16x16x32_bf16(a, b0, acc[mt][0], 0, 0, 0);
            acc[mt][1] = __builtin_amdgcn_mfma_f32_16x16x32_bf16(a, b1, acc[mt][1], 0, 0, 0);
        }
    }

    #pragma unroll
    for (int mt = 0; mt < MT; ++mt) {
        const int m0 = mt * 16 + quad * 4;
        #pragma unroll
        for (int nt = 0; nt < 2; ++nt) {
            const int node = base + nt * 16 + nn;
            if (node >= N_NODES) continue;
            v4f a = acc[mt][nt];
            const float4 bb = *(const float4*)(bias + m0);
            float x0 = a[0] + bb.x, x1 = a[1] + bb.y, x2 = a[2] + bb.z, x3 = a[3] + bb.w;
            if (RELU) {
                x0 = fmaxf(x0, 0.f); x1 = fmaxf(x1, 0.f);
                x2 = fmaxf(x2, 0.f); x3 = fmaxf(x3, 0.f);
            }
            uint2 o;
            o.x = f2bf(x0) | (f2bf(x1) << 16);
            o.y = f2bf(x2) | (f2bf(x3) << 16);
            *(uint2*)(out + (size_t)node * F + m0) = o;
        }
    }
}

// ---------------- layer-2: hn2 = h @ Wn2 (bf16 out, row stride 64) ----------------
// mean is linear: mean(h) @ Wn2 == mean(h @ Wn2). Transform first so the
// per-edge gather reads 128B rows instead of 256B.

__global__ __launch_bounds__(256)
void gemm_hn2_kernel(const unsigned short* __restrict__ h,
                     const unsigned short* __restrict__ wfrag,
                     unsigned short* __restrict__ hn2) {
    const int lane = threadIdx.x & 63;
    const int wave = threadIdx.x >> 6;
    const int quad = lane >> 4;
    const int nn   = lane & 15;
    const int base = blockIdx.x * 128 + wave * 32;

    const int n0 = base + nn;
    const int n1 = base + 16 + nn;
    const size_t r0 = (size_t)min(n0, N_NODES - 1) * F;
    const size_t r1 = (size_t)min(n1, N_NODES - 1) * F;

    v4f acc[3][2];
    #pragma unroll
    for (int mt = 0; mt < 3; ++mt) { acc[mt][0] = (v4f)0.f; acc[mt][1] = (v4f)0.f; }

    #pragma unroll
    for (int kt = 0; kt < 4; ++kt) {
        const int koff = kt * 32 + quad * 8;
        v8s b0 = *(const v8s*)(h + r0 + koff);
        v8s b1 = *(const v8s*)(h + r1 + koff);
        #pragma unroll
        for (int mt = 0; mt < 3; ++mt) {
            v8s a = *(const v8s*)(wfrag + ((size_t)(mt * 4 + kt) * 64 + lane) * 8);
            acc[mt][0] = __builtin_amdgcn_mfma_f32_16x16x32_bf16(a, b0, acc[mt][0], 0, 0, 0);
            acc[mt][1] = __builtin_amdgcn_mfma_f32_16x16x32_bf16(a, b1, acc[mt][1], 0, 0, 0);
        }
    }

    #pragma unroll
    for (int mt = 0; mt < 3; ++mt) {
        const int m0 = mt * 16 + quad * 4;   // 0..47
        #pragma unroll
        for (int nt = 0; nt < 2; ++nt) {
            const int node = base + nt * 16 + nn;
            if (node >= N_NODES) continue;
            v4f a = acc[mt][nt];
            uint2 o;
            o.x = f2bf(a[0]) | (f2bf(a[1]) << 16);
            o.y = f2bf(a[2]) | (f2bf(a[3]) << 16);
            *(uint2*)(hn2 + (size_t)node * 64 + m0) = o;
        }
    }
}

// ---------------- layer-2 final: out = mean2 + h @ Ws2 + b2 (fp32 out) ----------------

__global__ __launch_bounds__(256)
void final_kernel(const unsigned short* __restrict__ h,
                  const unsigned short* __restrict__ mean2,
                  const unsigned short* __restrict__ wfrag,
                  const float* __restrict__ bias,
                  float* __restrict__ out) {
    const int lane = threadIdx.x & 63;
    const int wave = threadIdx.x >> 6;
    const int quad = lane >> 4;
    const int nn   = lane & 15;
    const int base = blockIdx.x * 128 + wave * 32;

    const int n0 = base + nn;
    const int n1 = base + 16 + nn;
    const size_t r0 = (size_t)min(n0, N_NODES - 1) * F;
    const size_t r1 = (size_t)min(n1, N_NODES - 1) * F;

    v4f acc[3][2];
    #pragma unroll
    for (int mt = 0; mt < 3; ++mt) { acc[mt][0] = (v4f)0.f; acc[mt][1] = (v4f)0.f; }

    #pragma unroll
    for (int kt = 0; kt < 4; ++kt) {
        const int koff = kt * 32 + quad * 8;
        v8s b0 = *(const v8s*)(h + r0 + koff);
        v8s b1 = *(const v8s*)(h + r1 + koff);
        #pragma unroll
        for (int mt = 0; mt < 3; ++mt) {
            v8s a = *(const v8s*)(wfrag + ((size_t)(mt * 4 + kt) * 64 + lane) * 8);
            acc[mt][0] = __builtin_amdgcn_mfma_f32_16x16x32_bf16(a, b0, acc[mt][0], 0, 0, 0);
            acc[mt][1] = __builtin_amdgcn_mfma_f32_16x16x32_bf16(a, b1, acc[mt][1], 0, 0, 0);
        }
    }

    #pragma unroll
    for (int mt = 0; mt < 3; ++mt) {
        const int m0 = mt * 16 + quad * 4;   // 0..47, multiple of 4
        #pragma unroll
        for (int nt = 0; nt < 2; ++nt) {
            const int node = base + nt * 16 + nn;
            if (node >= N_NODES) continue;
            v4f a = acc[mt][nt];
            uint2 mv = *(const uint2*)(mean2 + (size_t)node * 64 + m0);
            float mf[4] = { bfl(mv.x), bfh(mv.x), bfl(mv.y), bfh(mv.y) };
            #pragma unroll
            for (int r = 0; r < 4; ++r) {
                int m = m0 + r;
                if (m < N_CLASSES)
                    out[(size_t)node * N_CLASSES + m] = a[r] + bias[m] + mf[r];
            }
        }
    }
}

// ---------------- launch ----------------

extern "C" void kernel_launch(void* const* d_in, const int* in_sizes, int n_in,
                              void* d_out, int out_size, void* d_ws, size_t ws_size,
                              hipStream_t stream) {
    const float* embed = (const float*)d_in[0];
    const float* Ws0   = (const float*)d_in[1];
    const float* Wn0   = (const float*)d_in[2];
    const float* b0    = (const float*)d_in[3];
    const float* Ws1   = (const float*)d_in[4];
    const float* Wn1   = (const float*)d_in[5];
    const float* b1    = (const float*)d_in[6];
    const float* Ws2   = (const float*)d_in[7];
    const float* Wn2   = (const float*)d_in[8];
    const float* b2    = (const float*)d_in[9];
    const int* input_nodes = (const int*)d_in[10];
    const int* src     = (const int*)d_in[11];
    const int* dst     = (const int*)d_in[12];
    float* out = (float*)d_out;

    char* ws = (char*)d_ws;
    size_t off = 0;
    auto alloc = [&](size_t bytes) -> void* {
        void* p = ws + off;
        off += (bytes + 255) & ~(size_t)255;
        return p;
    };
    int*            fillc    = (int*)           alloc(sizeof(int)   * N_NODES);
    float*          rdeg     = (float*)         alloc(sizeof(float) * N_NODES);
    int*            col      = (int*)           alloc(sizeof(int)   * (size_t)N_NODES * CAP);
    int*            gcnt     = (int*)           alloc(sizeof(int)   * NGRP);
    unsigned short* h_a      = (unsigned short*)alloc(2 * (size_t)N_NODES * F);
    unsigned short* h_b      = (unsigned short*)alloc(2 * (size_t)N_NODES * F);
    unsigned short* meanb    = (unsigned short*)alloc(2 * (size_t)N_NODES * F);
    unsigned short* wf0      = (unsigned short*)alloc(2 * 64 * 512);
    unsigned short* wf1      = (unsigned short*)alloc(2 * 64 * 512);
    unsigned short* wf2n     = (unsigned short*)alloc(2 * 12 * 512);
    unsigned short* wf2s     = (unsigned short*)alloc(2 * 12 * 512);
    (void)ws_size; (void)n_in; (void)in_sizes; (void)out_size;

    // staged edge pairs alias meanb: staged is dead before the first
    // aggregate writes meanb (same stream, serialized). 8*220000*8B = 14MB < 25.6MB.
    int2* staged = (int2*)meanb;

    hipMemsetAsync(fillc, 0, sizeof(int) * N_NODES, stream);
    hipMemsetAsync(gcnt,  0, sizeof(int) * NGRP,    stream);

    partition_kernel<<<PART_B, PART_T, 0, stream>>>(src, dst, gcnt, staged);
    scatter_kernel<<<4096, 256, 0, stream>>>(staged, gcnt, fillc, col);
    rdeg_kernel<<<(N_NODES + 255) / 256, 256, 0, stream>>>(fillc, rdeg);

    pack_w_kernel<<<64, 64, 0, stream>>>(Wn0, Ws0, F, wf0);
    pack_w_kernel<<<64, 64, 0, stream>>>(Wn1, Ws1, F, wf1);
    pack_w_single_kernel<<<12, 64, 0, stream>>>(Wn2, N_CLASSES, wf2n);
    pack_w_single_kernel<<<12, 64, 0, stream>>>(Ws2, N_CLASSES, wf2s);

    gather_embed_kernel<<<(N_NODES * (F / 4) + 255) / 256, 256, 0, stream>>>(embed, input_nodes, h_a);

    const int AGG_B  = (N_NODES + 3) / 4;
    const int GEMM_B = (N_NODES + 127) / 128;

    // layer 0: h_a -> h_b
    aggregate_kernel<<<AGG_B, 256, 0, stream>>>(h_a, fillc, col, rdeg, meanb);
    mfma_gemm_kernel<8, true><<<GEMM_B, 256, 0, stream>>>(meanb, h_a, wf0, b0, h_b);
    // layer 1: h_b -> h_a
    aggregate_kernel<<<AGG_B, 256, 0, stream>>>(h_b, fillc, col, rdeg, meanb);
    mfma_gemm_kernel<8, true><<<GEMM_B, 256, 0, stream>>>(meanb, h_b, wf1, b1, h_a);
    // layer 2 (transform-first): hn2 = h_a @ Wn2 (rows padded to 64, reuse h_b);
    // mean2 = mean-aggregate(hn2) (reuse meanb); out = mean2 + h_a @ Ws2 + b2
    gemm_hn2_kernel<<<GEMM_B, 256, 0, stream>>>(h_a, wf2n, h_b);
    aggregate48_kernel<<<AGG_B, 256, 0, stream>>>(h_b, fillc, col, rdeg, meanb);
    final_kernel<<<GEMM_B, 256, 0, stream>>>(h_a, meanb, wf2s, b2, out);
}

// Round 6
// 450.006 us; speedup vs baseline: 1.2617x; 1.1549x over previous
//
#include <hip/hip_runtime.h>

#define N_NODES   100000
#define N_EDGES   1600000
#define F         128
#define N_CLASSES 47

#define NBKT      256
#define GDIV2     391            // nodes per bucket (391*256 = 100096 >= 100000)
#define BCAP      7000           // staged capacity per bucket (Poisson mean 6250, +9.5 sd)
#define CAP       64             // col slab capacity per node (Poisson(16): P(>64)~1e-20)
#define EPT       32             // edges per thread in partition
#define PART_T    256
#define EPB       (PART_T * EPT) // 8192 edges per block
#define PART_B    ((N_EDGES + EPB - 1) / EPB)

typedef unsigned int uint32;

typedef short  v8s __attribute__((ext_vector_type(8)));   // 8 x bf16 (MFMA A/B frag)
typedef float  v4f __attribute__((ext_vector_type(4)));   // MFMA C/D frag

// bf16 helpers (RNE)
__device__ __forceinline__ uint32 f2bf(float f) {
    uint32 u = __float_as_uint(f);
    return (u + 0x7FFFu + ((u >> 16) & 1u)) >> 16;
}
__device__ __forceinline__ float bfl(uint32 u) { return __uint_as_float(u << 16); }
__device__ __forceinline__ float bfh(uint32 u) { return __uint_as_float(u & 0xFFFF0000u); }

// ---------------- phase A: bin edges into 256 node-range buckets ----------------
// Per block: LDS histogram (LDS atomics), ONE global atomic per bucket to
// reserve contiguous staged space (50K total, vs 1.6M per-edge before),
// LDS cursor for in-block rank, coalesced-ish segment writes.

__global__ __launch_bounds__(256)
void partition256_kernel(const int* __restrict__ src, const int* __restrict__ dst,
                         int* __restrict__ gcnt, int2* __restrict__ staged) {
    __shared__ int hist[NBKT];
    __shared__ int gbase[NBKT];
    const int tid = threadIdx.x;
    const int e0  = blockIdx.x * EPB;

    hist[tid] = 0;
    __syncthreads();

    int mys[EPT], myd[EPT];
    #pragma unroll
    for (int i = 0; i < EPT; ++i) {
        int e = e0 + i * PART_T + tid;
        bool val = (e < N_EDGES);
        mys[i] = val ? src[e] : 0;
        myd[i] = val ? dst[e] : -1;
        if (val) atomicAdd(&hist[myd[i] / GDIV2], 1);     // LDS atomic
    }
    __syncthreads();

    gbase[tid] = atomicAdd(&gcnt[tid], hist[tid]);        // 1 global atomic / bucket / block
    __syncthreads();
    hist[tid] = 0;                                        // reuse as cursor
    __syncthreads();

    #pragma unroll
    for (int i = 0; i < EPT; ++i) {
        if (myd[i] >= 0) {
            int b = myd[i] / GDIV2;
            int r = atomicAdd(&hist[b], 1);               // LDS cursor rank
            int idx = gbase[b] + r;
            if (idx < BCAP)
                staged[(size_t)b * BCAP + idx] = make_int2(mys[i], myd[i]);
        }
    }
}

// ---------------- phase B: per-bucket scatter with LDS counters (zero global atomics) ----
// One block per bucket: stream the bucket's staged slice (sequential ~50KB),
// rank via LDS atomicAdd, write col inside a 100KB window. Emits deg/rdeg.

__global__ __launch_bounds__(256)
void bucket_scatter_kernel(const int2* __restrict__ staged, const int* __restrict__ gcnt,
                           int* __restrict__ fillc, float* __restrict__ rdeg,
                           int* __restrict__ col) {
    __shared__ int cnt[GDIV2];
    const int b     = blockIdx.x;
    const int tid   = threadIdx.x;
    const int node0 = b * GDIV2;

    for (int i = tid; i < GDIV2; i += 256) cnt[i] = 0;
    __syncthreads();

    const int n = min(gcnt[b], BCAP);
    const int2* sp = staged + (size_t)b * BCAP;
    for (int i = tid; i < n; i += 256) {
        int2 sd = sp[i];
        int c = atomicAdd(&cnt[sd.y - node0], 1);         // LDS atomic
        if (c < CAP) col[(size_t)sd.y * CAP + c] = sd.x;
    }
    __syncthreads();

    for (int i = tid; i < GDIV2; i += 256) {
        int v = node0 + i;
        if (v < N_NODES) {
            int d = min(cnt[i], CAP);
            fillc[v] = d;
            rdeg[v]  = 1.0f / (float)max(d, 1);
        }
    }
}

// ---------------- weight pre-pack: fp32 Wn/Ws -> bf16 MFMA A-frags ----------------

__global__ void pack_w_kernel(const float* __restrict__ Wn, const float* __restrict__ Ws,
                              int nout, unsigned short* __restrict__ wfrag) {
    int tile = blockIdx.x;           // mt*8 + kt
    int kt   = tile & 7;
    int mt   = tile >> 3;
    int lane = threadIdx.x;          // 64
    int quad = lane >> 4;
    int m    = mt * 16 + (lane & 15);
    uint32 packed[4];
    #pragma unroll
    for (int jj = 0; jj < 4; ++jj) {
        uint32 lo = 0, hi = 0;
        #pragma unroll
        for (int b = 0; b < 2; ++b) {
            int j = jj * 2 + b;
            int k = kt * 32 + quad * 8 + j;
            float w = 0.f;
            if (m < nout) w = (k < F) ? Wn[(size_t)k * nout + m] : Ws[(size_t)(k - F) * nout + m];
            if (b == 0) lo = f2bf(w); else hi = f2bf(w);
        }
        packed[jj] = lo | (hi << 16);
    }
    uint4 o = make_uint4(packed[0], packed[1], packed[2], packed[3]);
    *(uint4*)(wfrag + ((size_t)tile * 64 + lane) * 8) = o;
}

// single-W pack (K=128, 4 k-tiles): tile = mt*4 + kt
__global__ void pack_w_single_kernel(const float* __restrict__ W, int nout,
                                     unsigned short* __restrict__ wfrag) {
    int tile = blockIdx.x;
    int kt   = tile & 3;
    int mt   = tile >> 2;
    int lane = threadIdx.x;
    int quad = lane >> 4;
    int m    = mt * 16 + (lane & 15);
    uint32 packed[4];
    #pragma unroll
    for (int jj = 0; jj < 4; ++jj) {
        uint32 lo = 0, hi = 0;
        #pragma unroll
        for (int b = 0; b < 2; ++b) {
            int k = kt * 32 + quad * 8 + jj * 2 + b;
            float w = (m < nout) ? W[(size_t)k * nout + m] : 0.f;
            if (b == 0) lo = f2bf(w); else hi = f2bf(w);
        }
        packed[jj] = lo | (hi << 16);
    }
    uint4 o = make_uint4(packed[0], packed[1], packed[2], packed[3]);
    *(uint4*)(wfrag + ((size_t)tile * 64 + lane) * 8) = o;
}

// ---------------- embedding gather: fp32 embed -> bf16 h ----------------

__global__ void gather_embed_kernel(const float* __restrict__ embed,
                                    const int* __restrict__ idx,
                                    unsigned short* __restrict__ h) {
    int i = blockIdx.x * blockDim.x + threadIdx.x;
    const int TOTAL = N_NODES * (F / 4);
    if (i < TOTAL) {
        int node = i >> 5;
        int c4 = i & 31;
        float4 v = ((const float4*)(embed + (size_t)idx[node] * F))[c4];
        uint2 o;
        o.x = f2bf(v.x) | (f2bf(v.y) << 16);
        o.y = f2bf(v.z) | (f2bf(v.w) << 16);
        ((uint2*)(h + (size_t)node * F))[c4] = o;
    }
}

// ---------------- pull aggregation (bf16 h -> bf16 mean, fp32 accum) ----------------
// one wave per node; 4 sub-groups x 16 lanes; each sub-group loads a FULL
// 256B neighbor row as uint4 (16B/lane) -> 4 edges per iter. col slab is
// v*CAP .. v*CAP+deg. Prefetch index clamped to the initialized region.

__global__ void aggregate_kernel(const unsigned short* __restrict__ h,
                                 const int* __restrict__ deg,
                                 const int* __restrict__ col,
                                 const float* __restrict__ rdeg,
                                 unsigned short* __restrict__ mean) {
    const int wave = threadIdx.x >> 6;
    const int lane = threadIdx.x & 63;
    const int sub  = lane >> 4;          // which of 4 edges per iter
    const int li   = lane & 15;          // 16B slot within the row
    const int v    = blockIdx.x * 4 + wave;
    if (v >= N_NODES) return;

    const uint4* hp4 = (const uint4*)h;  // 16 uint4 per 256B row
    const int beg = v * CAP;
    const int end = beg + deg[v];
    const int dmax = max(end - 1, beg);  // clamp: padded slots are garbage

    float a0 = 0.f, a1 = 0.f, a2 = 0.f, a3 = 0.f;
    float a4 = 0.f, a5 = 0.f, a6 = 0.f, a7 = 0.f;

    int p = beg;
    int u = col[min(p + sub, dmax)];     // prefetch (clamped)
    #pragma unroll 2
    for (; p + 4 <= end; p += 4) {
        int un = col[min(p + 4 + sub, dmax)];
        uint4 x = hp4[(size_t)u * 16 + li];
        a0 += bfl(x.x); a1 += bfh(x.x);
        a2 += bfl(x.y); a3 += bfh(x.y);
        a4 += bfl(x.z); a5 += bfh(x.z);
        a6 += bfl(x.w); a7 += bfh(x.w);
        u = un;
    }
    if (p + sub < end) {                 // tail (u prefetched from valid slot)
        uint4 x = hp4[(size_t)u * 16 + li];
        a0 += bfl(x.x); a1 += bfh(x.x);
        a2 += bfl(x.y); a3 += bfh(x.y);
        a4 += bfl(x.z); a5 += bfh(x.z);
        a6 += bfl(x.w); a7 += bfh(x.w);
    }

    #pragma unroll
    for (int m = 16; m <= 32; m <<= 1) {
        a0 += __shfl_xor(a0, m, 64);
        a1 += __shfl_xor(a1, m, 64);
        a2 += __shfl_xor(a2, m, 64);
        a3 += __shfl_xor(a3, m, 64);
        a4 += __shfl_xor(a4, m, 64);
        a5 += __shfl_xor(a5, m, 64);
        a6 += __shfl_xor(a6, m, 64);
        a7 += __shfl_xor(a7, m, 64);
    }

    if (sub == 0) {
        const float r = rdeg[v];
        uint4 o;
        o.x = f2bf(a0 * r) | (f2bf(a1 * r) << 16);
        o.y = f2bf(a2 * r) | (f2bf(a3 * r) << 16);
        o.z = f2bf(a4 * r) | (f2bf(a5 * r) << 16);
        o.w = f2bf(a6 * r) | (f2bf(a7 * r) << 16);
        ((uint4*)mean)[(size_t)v * 16 + li] = o;
    }
}

// 48-wide aggregation over 128B rows (layer 2, post-transform).
// 8 sub-groups x 8 lanes; each sub-group loads a full 128B row (uint4/lane).

__global__ void aggregate48_kernel(const unsigned short* __restrict__ hn,
                                   const int* __restrict__ deg,
                                   const int* __restrict__ col,
                                   const float* __restrict__ rdeg,
                                   unsigned short* __restrict__ mean) {
    const int wave = threadIdx.x >> 6;
    const int lane = threadIdx.x & 63;
    const int sub  = lane >> 3;          // which of 8 edges per iter
    const int li   = lane & 7;           // 16B slot within the 128B row
    const int v    = blockIdx.x * 4 + wave;
    if (v >= N_NODES) return;

    const uint4* hp4 = (const uint4*)hn; // 8 uint4 per 128B row
    const int beg = v * CAP;
    const int end = beg + deg[v];
    const int dmax = max(end - 1, beg);

    float a0 = 0.f, a1 = 0.f, a2 = 0.f, a3 = 0.f;
    float a4 = 0.f, a5 = 0.f, a6 = 0.f, a7 = 0.f;

    int p = beg;
    int u = col[min(p + sub, dmax)];
    #pragma unroll 2
    for (; p + 8 <= end; p += 8) {
        int un = col[min(p + 8 + sub, dmax)];
        uint4 x = hp4[(size_t)u * 8 + li];
        a0 += bfl(x.x); a1 += bfh(x.x);
        a2 += bfl(x.y); a3 += bfh(x.y);
        a4 += bfl(x.z); a5 += bfh(x.z);
        a6 += bfl(x.w); a7 += bfh(x.w);
        u = un;
    }
    if (p + sub < end) {
        uint4 x = hp4[(size_t)u * 8 + li];
        a0 += bfl(x.x); a1 += bfh(x.x);
        a2 += bfl(x.y); a3 += bfh(x.y);
        a4 += bfl(x.z); a5 += bfh(x.z);
        a6 += bfl(x.w); a7 += bfh(x.w);
    }

    #pragma unroll
    for (int m = 8; m <= 32; m <<= 1) {
        a0 += __shfl_xor(a0, m, 64);
        a1 += __shfl_xor(a1, m, 64);
        a2 += __shfl_xor(a2, m, 64);
        a3 += __shfl_xor(a3, m, 64);
        a4 += __shfl_xor(a4, m, 64);
        a5 += __shfl_xor(a5, m, 64);
        a6 += __shfl_xor(a6, m, 64);
        a7 += __shfl_xor(a7, m, 64);
    }

    if (sub == 0) {
        const float r = rdeg[v];
        uint4 o;
        o.x = f2bf(a0 * r) | (f2bf(a1 * r) << 16);
        o.y = f2bf(a2 * r) | (f2bf(a3 * r) << 16);
        o.z = f2bf(a4 * r) | (f2bf(a5 * r) << 16);
        o.w = f2bf(a6 * r) | (f2bf(a7 * r) << 16);
        ((uint4*)mean)[(size_t)v * 8 + li] = o;
    }
}

// ---------------- MFMA GEMM: out = [mean|h] @ Wcat + b (+relu), bf16 out ----------------

template<int MT, bool RELU>
__global__ __launch_bounds__(256)
void mfma_gemm_kernel(const unsigned short* __restrict__ meanb,
                      const unsigned short* __restrict__ h,
                      const unsigned short* __restrict__ wfrag,
                      const float* __restrict__ bias,
                      unsigned short* __restrict__ out) {
    const int lane = threadIdx.x & 63;
    const int wave = threadIdx.x >> 6;
    const int quad = lane >> 4;
    const int nn   = lane & 15;
    const int base = blockIdx.x * 128 + wave * 32;

    const int n0 = base + nn;
    const int n1 = base + 16 + nn;
    const size_t r0 = (size_t)min(n0, N_NODES - 1) * F;
    const size_t r1 = (size_t)min(n1, N_NODES - 1) * F;

    v4f acc[MT][2];
    #pragma unroll
    for (int mt = 0; mt < MT; ++mt) { acc[mt][0] = (v4f)0.f; acc[mt][1] = (v4f)0.f; }

    #pragma unroll
    for (int kt = 0; kt < 8; ++kt) {
        const unsigned short* B = (kt < 4) ? meanb : h;
        const int koff = (kt & 3) * 32 + quad * 8;
        v8s b0 = *(const v8s*)(B + r0 + koff);
        v8s b1 = *(const v8s*)(B + r1 + koff);
        #pragma unroll
        for (int mt = 0; mt < MT; ++mt) {
            v8s a = *(const v8s*)(wfrag + ((size_t)(mt * 8 + kt) * 64 + lane) * 8);
            acc[mt][0] = __builtin_amdgcn_mfma_f32_16x16x32_bf16(a, b0, acc[mt][0], 0, 0, 0);
            acc[mt][1] = __builtin_amdgcn_mfma_f32_16x16x32_bf16(a, b1, acc[mt][1], 0, 0, 0);
        }
    }

    #pragma unroll
    for (int mt = 0; mt < MT; ++mt) {
        const int m0 = mt * 16 + quad * 4;
        #pragma unroll
        for (int nt = 0; nt < 2; ++nt) {
            const int node = base + nt * 16 + nn;
            if (node >= N_NODES) continue;
            v4f a = acc[mt][nt];
            const float4 bb = *(const float4*)(bias + m0);
            float x0 = a[0] + bb.x, x1 = a[1] + bb.y, x2 = a[2] + bb.z, x3 = a[3] + bb.w;
            if (RELU) {
                x0 = fmaxf(x0, 0.f); x1 = fmaxf(x1, 0.f);
                x2 = fmaxf(x2, 0.f); x3 = fmaxf(x3, 0.f);
            }
            uint2 o;
            o.x = f2bf(x0) | (f2bf(x1) << 16);
            o.y = f2bf(x2) | (f2bf(x3) << 16);
            *(uint2*)(out + (size_t)node * F + m0) = o;
        }
    }
}

// ---------------- layer-2: hn2 = h @ Wn2 (bf16 out, row stride 64) ----------------
// mean is linear: mean(h) @ Wn2 == mean(h @ Wn2). Transform first so the
// per-edge gather reads 128B rows instead of 256B.

__global__ __launch_bounds__(256)
void gemm_hn2_kernel(const unsigned short* __restrict__ h,
                     const unsigned short* __restrict__ wfrag,
                     unsigned short* __restrict__ hn2) {
    const int lane = threadIdx.x & 63;
    const int wave = threadIdx.x >> 6;
    const int quad = lane >> 4;
    const int nn   = lane & 15;
    const int base = blockIdx.x * 128 + wave * 32;

    const int n0 = base + nn;
    const int n1 = base + 16 + nn;
    const size_t r0 = (size_t)min(n0, N_NODES - 1) * F;
    const size_t r1 = (size_t)min(n1, N_NODES - 1) * F;

    v4f acc[3][2];
    #pragma unroll
    for (int mt = 0; mt < 3; ++mt) { acc[mt][0] = (v4f)0.f; acc[mt][1] = (v4f)0.f; }

    #pragma unroll
    for (int kt = 0; kt < 4; ++kt) {
        const int koff = kt * 32 + quad * 8;
        v8s b0 = *(const v8s*)(h + r0 + koff);
        v8s b1 = *(const v8s*)(h + r1 + koff);
        #pragma unroll
        for (int mt = 0; mt < 3; ++mt) {
            v8s a = *(const v8s*)(wfrag + ((size_t)(mt * 4 + kt) * 64 + lane) * 8);
            acc[mt][0] = __builtin_amdgcn_mfma_f32_16x16x32_bf16(a, b0, acc[mt][0], 0, 0, 0);
            acc[mt][1] = __builtin_amdgcn_mfma_f32_16x16x32_bf16(a, b1, acc[mt][1], 0, 0, 0);
        }
    }

    #pragma unroll
    for (int mt = 0; mt < 3; ++mt) {
        const int m0 = mt * 16 + quad * 4;   // 0..47
        #pragma unroll
        for (int nt = 0; nt < 2; ++nt) {
            const int node = base + nt * 16 + nn;
            if (node >= N_NODES) continue;
            v4f a = acc[mt][nt];
            uint2 o;
            o.x = f2bf(a[0]) | (f2bf(a[1]) << 16);
            o.y = f2bf(a[2]) | (f2bf(a[3]) << 16);
            *(uint2*)(hn2 + (size_t)node * 64 + m0) = o;
        }
    }
}

// ---------------- layer-2 final: out = mean2 + h @ Ws2 + b2 (fp32 out) ----------------

__global__ __launch_bounds__(256)
void final_kernel(const unsigned short* __restrict__ h,
                  const unsigned short* __restrict__ mean2,
                  const unsigned short* __restrict__ wfrag,
                  const float* __restrict__ bias,
                  float* __restrict__ out) {
    const int lane = threadIdx.x & 63;
    const int wave = threadIdx.x >> 6;
    const int quad = lane >> 4;
    const int nn   = lane & 15;
    const int base = blockIdx.x * 128 + wave * 32;

    const int n0 = base + nn;
    const int n1 = base + 16 + nn;
    const size_t r0 = (size_t)min(n0, N_NODES - 1) * F;
    const size_t r1 = (size_t)min(n1, N_NODES - 1) * F;

    v4f acc[3][2];
    #pragma unroll
    for (int mt = 0; mt < 3; ++mt) { acc[mt][0] = (v4f)0.f; acc[mt][1] = (v4f)0.f; }

    #pragma unroll
    for (int kt = 0; kt < 4; ++kt) {
        const int koff = kt * 32 + quad * 8;
        v8s b0 = *(const v8s*)(h + r0 + koff);
        v8s b1 = *(const v8s*)(h + r1 + koff);
        #pragma unroll
        for (int mt = 0; mt < 3; ++mt) {
            v8s a = *(const v8s*)(wfrag + ((size_t)(mt * 4 + kt) * 64 + lane) * 8);
            acc[mt][0] = __builtin_amdgcn_mfma_f32_16x16x32_bf16(a, b0, acc[mt][0], 0, 0, 0);
            acc[mt][1] = __builtin_amdgcn_mfma_f32_16x16x32_bf16(a, b1, acc[mt][1], 0, 0, 0);
        }
    }

    #pragma unroll
    for (int mt = 0; mt < 3; ++mt) {
        const int m0 = mt * 16 + quad * 4;   // 0..47, multiple of 4
        #pragma unroll
        for (int nt = 0; nt < 2; ++nt) {
            const int node = base + nt * 16 + nn;
            if (node >= N_NODES) continue;
            v4f a = acc[mt][nt];
            uint2 mv = *(const uint2*)(mean2 + (size_t)node * 64 + m0);
            float mf[4] = { bfl(mv.x), bfh(mv.x), bfl(mv.y), bfh(mv.y) };
            #pragma unroll
            for (int r = 0; r < 4; ++r) {
                int m = m0 + r;
                if (m < N_CLASSES)
                    out[(size_t)node * N_CLASSES + m] = a[r] + bias[m] + mf[r];
            }
        }
    }
}

// ---------------- launch ----------------

extern "C" void kernel_launch(void* const* d_in, const int* in_sizes, int n_in,
                              void* d_out, int out_size, void* d_ws, size_t ws_size,
                              hipStream_t stream) {
    const float* embed = (const float*)d_in[0];
    const float* Ws0   = (const float*)d_in[1];
    const float* Wn0   = (const float*)d_in[2];
    const float* b0    = (const float*)d_in[3];
    const float* Ws1   = (const float*)d_in[4];
    const float* Wn1   = (const float*)d_in[5];
    const float* b1    = (const float*)d_in[6];
    const float* Ws2   = (const float*)d_in[7];
    const float* Wn2   = (const float*)d_in[8];
    const float* b2    = (const float*)d_in[9];
    const int* input_nodes = (const int*)d_in[10];
    const int* src     = (const int*)d_in[11];
    const int* dst     = (const int*)d_in[12];
    float* out = (float*)d_out;

    char* ws = (char*)d_ws;
    size_t off = 0;
    auto alloc = [&](size_t bytes) -> void* {
        void* p = ws + off;
        off += (bytes + 255) & ~(size_t)255;
        return p;
    };
    int*            fillc    = (int*)           alloc(sizeof(int)   * N_NODES);
    float*          rdeg     = (float*)         alloc(sizeof(float) * N_NODES);
    int*            col      = (int*)           alloc(sizeof(int)   * (size_t)N_NODES * CAP);
    int*            gcnt     = (int*)           alloc(sizeof(int)   * NBKT);
    unsigned short* h_a      = (unsigned short*)alloc(2 * (size_t)N_NODES * F);
    unsigned short* h_b      = (unsigned short*)alloc(2 * (size_t)N_NODES * F);
    unsigned short* meanb    = (unsigned short*)alloc(2 * (size_t)N_NODES * F);
    unsigned short* wf0      = (unsigned short*)alloc(2 * 64 * 512);
    unsigned short* wf1      = (unsigned short*)alloc(2 * 64 * 512);
    unsigned short* wf2n     = (unsigned short*)alloc(2 * 12 * 512);
    unsigned short* wf2s     = (unsigned short*)alloc(2 * 12 * 512);
    (void)ws_size; (void)n_in; (void)in_sizes; (void)out_size;

    // staged edge pairs alias meanb: staged is dead before the first
    // aggregate writes meanb (same stream, serialized). 256*7000*8B = 14.3MB < 25.6MB.
    int2* staged = (int2*)meanb;

    hipMemsetAsync(gcnt, 0, sizeof(int) * NBKT, stream);

    partition256_kernel<<<PART_B, PART_T, 0, stream>>>(src, dst, gcnt, staged);
    bucket_scatter_kernel<<<NBKT, 256, 0, stream>>>(staged, gcnt, fillc, rdeg, col);

    pack_w_kernel<<<64, 64, 0, stream>>>(Wn0, Ws0, F, wf0);
    pack_w_kernel<<<64, 64, 0, stream>>>(Wn1, Ws1, F, wf1);
    pack_w_single_kernel<<<12, 64, 0, stream>>>(Wn2, N_CLASSES, wf2n);
    pack_w_single_kernel<<<12, 64, 0, stream>>>(Ws2, N_CLASSES, wf2s);

    gather_embed_kernel<<<(N_NODES * (F / 4) + 255) / 256, 256, 0, stream>>>(embed, input_nodes, h_a);

    const int AGG_B  = (N_NODES + 3) / 4;
    const int GEMM_B = (N_NODES + 127) / 128;

    // layer 0: h_a -> h_b
    aggregate_kernel<<<AGG_B, 256, 0, stream>>>(h_a, fillc, col, rdeg, meanb);
    mfma_gemm_kernel<8, true><<<GEMM_B, 256, 0, stream>>>(meanb, h_a, wf0, b0, h_b);
    // layer 1: h_b -> h_a
    aggregate_kernel<<<AGG_B, 256, 0, stream>>>(h_b, fillc, col, rdeg, meanb);
    mfma_gemm_kernel<8, true><<<GEMM_B, 256, 0, stream>>>(meanb, h_b, wf1, b1, h_a);
    // layer 2 (transform-first): hn2 = h_a @ Wn2 (rows padded to 64, reuse h_b);
    // mean2 = mean-aggregate(hn2) (reuse meanb); out = mean2 + h_a @ Ws2 + b2
    gemm_hn2_kernel<<<GEMM_B, 256, 0, stream>>>(h_a, wf2n, h_b);
    aggregate48_kernel<<<AGG_B, 256, 0, stream>>>(h_b, fillc, col, rdeg, meanb);
    final_kernel<<<GEMM_B, 256, 0, stream>>>(h_a, meanb, wf2s, b2, out);
}

// Round 7
// 386.783 us; speedup vs baseline: 1.4679x; 1.1635x over previous
//
#include <hip/hip_runtime.h>

#define N_NODES   100000
#define N_EDGES   1600000
#define F         128
#define N_CLASSES 47

#define NBKT      256
#define GDIV2     391            // nodes per bucket (391*256 = 100096 >= 100000)
#define BCAP      7000           // staged capacity per bucket (Poisson mean 6250, +9.5 sd)
#define CAP       64             // col slab capacity per node (Poisson(16): P(>64)~1e-20)
#define EPT       32             // edges per thread in partition
#define PART_T    256
#define EPB       (PART_T * EPT) // 8192 edges per block
#define PART_B    ((N_EDGES + EPB - 1) / EPB)

typedef unsigned int uint32;

typedef short  v8s __attribute__((ext_vector_type(8)));   // 8 x bf16 (MFMA A/B frag)
typedef float  v4f __attribute__((ext_vector_type(4)));   // MFMA C/D frag

// bf16 helpers (RNE)
__device__ __forceinline__ uint32 f2bf(float f) {
    uint32 u = __float_as_uint(f);
    return (u + 0x7FFFu + ((u >> 16) & 1u)) >> 16;
}
__device__ __forceinline__ float bfl(uint32 u) { return __uint_as_float(u << 16); }
__device__ __forceinline__ float bfh(uint32 u) { return __uint_as_float(u & 0xFFFF0000u); }

// ---------------- phase A: bin edges into 256 node-range buckets ----------------

__global__ __launch_bounds__(256)
void partition256_kernel(const int* __restrict__ src, const int* __restrict__ dst,
                         int* __restrict__ gcnt, int2* __restrict__ staged) {
    __shared__ int hist[NBKT];
    __shared__ int gbase[NBKT];
    const int tid = threadIdx.x;
    const int e0  = blockIdx.x * EPB;

    hist[tid] = 0;
    __syncthreads();

    int mys[EPT], myd[EPT];
    #pragma unroll
    for (int i = 0; i < EPT; ++i) {
        int e = e0 + i * PART_T + tid;
        bool val = (e < N_EDGES);
        mys[i] = val ? src[e] : 0;
        myd[i] = val ? dst[e] : -1;
        if (val) atomicAdd(&hist[myd[i] / GDIV2], 1);     // LDS atomic
    }
    __syncthreads();

    gbase[tid] = atomicAdd(&gcnt[tid], hist[tid]);        // 1 global atomic / bucket / block
    __syncthreads();
    hist[tid] = 0;                                        // reuse as cursor
    __syncthreads();

    #pragma unroll
    for (int i = 0; i < EPT; ++i) {
        if (myd[i] >= 0) {
            int b = myd[i] / GDIV2;
            int r = atomicAdd(&hist[b], 1);               // LDS cursor rank
            int idx = gbase[b] + r;
            if (idx < BCAP)
                staged[(size_t)b * BCAP + idx] = make_int2(mys[i], myd[i]);
        }
    }
}

// ---------------- phase B: per-bucket scatter with LDS counters ----------------

__global__ __launch_bounds__(256)
void bucket_scatter_kernel(const int2* __restrict__ staged, const int* __restrict__ gcnt,
                           int* __restrict__ fillc, float* __restrict__ rdeg,
                           int* __restrict__ col) {
    __shared__ int cnt[GDIV2];
    const int b     = blockIdx.x;
    const int tid   = threadIdx.x;
    const int node0 = b * GDIV2;

    for (int i = tid; i < GDIV2; i += 256) cnt[i] = 0;
    __syncthreads();

    const int n = min(gcnt[b], BCAP);
    const int2* sp = staged + (size_t)b * BCAP;
    for (int i = tid; i < n; i += 256) {
        int2 sd = sp[i];
        int c = atomicAdd(&cnt[sd.y - node0], 1);         // LDS atomic
        if (c < CAP) col[(size_t)sd.y * CAP + c] = sd.x;
    }
    __syncthreads();

    for (int i = tid; i < GDIV2; i += 256) {
        int v = node0 + i;
        if (v < N_NODES) {
            int d = min(cnt[i], CAP);
            fillc[v] = d;
            rdeg[v]  = 1.0f / (float)max(d, 1);
        }
    }
}

// ---------------- weight pre-pack: fp32 Wn/Ws -> bf16 MFMA A-frags ----------------

__global__ void pack_w_kernel(const float* __restrict__ Wn, const float* __restrict__ Ws,
                              int nout, unsigned short* __restrict__ wfrag) {
    int tile = blockIdx.x;           // mt*8 + kt
    int kt   = tile & 7;
    int mt   = tile >> 3;
    int lane = threadIdx.x;          // 64
    int quad = lane >> 4;
    int m    = mt * 16 + (lane & 15);
    uint32 packed[4];
    #pragma unroll
    for (int jj = 0; jj < 4; ++jj) {
        uint32 lo = 0, hi = 0;
        #pragma unroll
        for (int b = 0; b < 2; ++b) {
            int j = jj * 2 + b;
            int k = kt * 32 + quad * 8 + j;
            float w = 0.f;
            if (m < nout) w = (k < F) ? Wn[(size_t)k * nout + m] : Ws[(size_t)(k - F) * nout + m];
            if (b == 0) lo = f2bf(w); else hi = f2bf(w);
        }
        packed[jj] = lo | (hi << 16);
    }
    uint4 o = make_uint4(packed[0], packed[1], packed[2], packed[3]);
    *(uint4*)(wfrag + ((size_t)tile * 64 + lane) * 8) = o;
}

// single-W pack (K=128, 4 k-tiles): tile = mt*4 + kt
__global__ void pack_w_single_kernel(const float* __restrict__ W, int nout,
                                     unsigned short* __restrict__ wfrag) {
    int tile = blockIdx.x;
    int kt   = tile & 3;
    int mt   = tile >> 2;
    int lane = threadIdx.x;
    int quad = lane >> 4;
    int m    = mt * 16 + (lane & 15);
    uint32 packed[4];
    #pragma unroll
    for (int jj = 0; jj < 4; ++jj) {
        uint32 lo = 0, hi = 0;
        #pragma unroll
        for (int b = 0; b < 2; ++b) {
            int k = kt * 32 + quad * 8 + jj * 2 + b;
            float w = (m < nout) ? W[(size_t)k * nout + m] : 0.f;
            if (b == 0) lo = f2bf(w); else hi = f2bf(w);
        }
        packed[jj] = lo | (hi << 16);
    }
    uint4 o = make_uint4(packed[0], packed[1], packed[2], packed[3]);
    *(uint4*)(wfrag + ((size_t)tile * 64 + lane) * 8) = o;
}

// ---------------- embedding gather: fp32 embed -> bf16 h ----------------

__global__ void gather_embed_kernel(const float* __restrict__ embed,
                                    const int* __restrict__ idx,
                                    unsigned short* __restrict__ h) {
    int i = blockIdx.x * blockDim.x + threadIdx.x;
    const int TOTAL = N_NODES * (F / 4);
    if (i < TOTAL) {
        int node = i >> 5;
        int c4 = i & 31;
        float4 v = ((const float4*)(embed + (size_t)idx[node] * F))[c4];
        uint2 o;
        o.x = f2bf(v.x) | (f2bf(v.y) << 16);
        o.y = f2bf(v.z) | (f2bf(v.w) << 16);
        ((uint2*)(h + (size_t)node * F))[c4] = o;
    }
}

// ---------------- fused layer (layers 0/1): aggregate 32 nodes -> LDS mean tile,
// then out = [mean|h] @ Wcat + b (+relu), bf16 out. Kills meanb round-trip.
// Block = 32 nodes, 4 waves; phase 1: each wave aggregates 8 nodes (4 sub x 16
// lanes, full 256B rows); phase 2: per-wave 2 m-tiles of the MFMA GEMM,
// B-operand kt<4 from LDS (rows padded to 272B: stride/4 = 68 -> rotating
// banks, benign), kt>=4 self rows from global.

__global__ __launch_bounds__(256)
void fused_layer_kernel(const unsigned short* __restrict__ h,
                        const int* __restrict__ deg,
                        const int* __restrict__ col,
                        const float* __restrict__ rdeg,
                        const unsigned short* __restrict__ wfrag,
                        const float* __restrict__ bias,
                        unsigned short* __restrict__ out) {
    __shared__ unsigned short Bm[32][136];   // 32 x 128 mean tile, +8 pad

    const int wv   = threadIdx.x >> 6;
    const int lane = threadIdx.x & 63;
    const int sub  = lane >> 4;
    const int li   = lane & 15;
    const int base = blockIdx.x * 32;        // grid 3125 * 32 = 100000 exact

    const uint4* hp4 = (const uint4*)h;

    // ---- phase 1: aggregate 8 nodes per wave ----
    for (int j = 0; j < 8; ++j) {
        const int v   = base + wv * 8 + j;
        const int beg = v * CAP;
        const int end = beg + deg[v];
        const int dmax = max(end - 1, beg);

        float a0 = 0.f, a1 = 0.f, a2 = 0.f, a3 = 0.f;
        float a4 = 0.f, a5 = 0.f, a6 = 0.f, a7 = 0.f;

        int p = beg;
        int u = col[min(p + sub, dmax)];
        #pragma unroll 2
        for (; p + 4 <= end; p += 4) {
            int un = col[min(p + 4 + sub, dmax)];
            uint4 x = hp4[(size_t)u * 16 + li];
            a0 += bfl(x.x); a1 += bfh(x.x);
            a2 += bfl(x.y); a3 += bfh(x.y);
            a4 += bfl(x.z); a5 += bfh(x.z);
            a6 += bfl(x.w); a7 += bfh(x.w);
            u = un;
        }
        if (p + sub < end) {
            uint4 x = hp4[(size_t)u * 16 + li];
            a0 += bfl(x.x); a1 += bfh(x.x);
            a2 += bfl(x.y); a3 += bfh(x.y);
            a4 += bfl(x.z); a5 += bfh(x.z);
            a6 += bfl(x.w); a7 += bfh(x.w);
        }

        #pragma unroll
        for (int m = 16; m <= 32; m <<= 1) {
            a0 += __shfl_xor(a0, m, 64);
            a1 += __shfl_xor(a1, m, 64);
            a2 += __shfl_xor(a2, m, 64);
            a3 += __shfl_xor(a3, m, 64);
            a4 += __shfl_xor(a4, m, 64);
            a5 += __shfl_xor(a5, m, 64);
            a6 += __shfl_xor(a6, m, 64);
            a7 += __shfl_xor(a7, m, 64);
        }

        if (sub == 0) {
            const float r = rdeg[v];
            uint4 o;
            o.x = f2bf(a0 * r) | (f2bf(a1 * r) << 16);
            o.y = f2bf(a2 * r) | (f2bf(a3 * r) << 16);
            o.z = f2bf(a4 * r) | (f2bf(a5 * r) << 16);
            o.w = f2bf(a6 * r) | (f2bf(a7 * r) << 16);
            *(uint4*)&Bm[wv * 8 + j][li * 8] = o;
        }
    }
    __syncthreads();

    // ---- phase 2: GEMM, wave wv handles m-tiles {2wv, 2wv+1} ----
    const int quad = sub;
    const int nn   = li;
    const size_t r0 = (size_t)(base + nn) * F;
    const size_t r1 = (size_t)(base + 16 + nn) * F;

    v4f acc[2][2];
    acc[0][0] = (v4f)0.f; acc[0][1] = (v4f)0.f;
    acc[1][0] = (v4f)0.f; acc[1][1] = (v4f)0.f;

    #pragma unroll
    for (int kt = 0; kt < 8; ++kt) {
        const int koff = (kt & 3) * 32 + quad * 8;
        v8s b0, b1;
        if (kt < 4) {
            b0 = *(const v8s*)&Bm[nn][koff];
            b1 = *(const v8s*)&Bm[nn + 16][koff];
        } else {
            b0 = *(const v8s*)(h + r0 + koff);
            b1 = *(const v8s*)(h + r1 + koff);
        }
        #pragma unroll
        for (int m2 = 0; m2 < 2; ++m2) {
            const int mt = wv * 2 + m2;
            v8s a = *(const v8s*)(wfrag + ((size_t)(mt * 8 + kt) * 64 + lane) * 8);
            acc[m2][0] = __builtin_amdgcn_mfma_f32_16x16x32_bf16(a, b0, acc[m2][0], 0, 0, 0);
            acc[m2][1] = __builtin_amdgcn_mfma_f32_16x16x32_bf16(a, b1, acc[m2][1], 0, 0, 0);
        }
    }

    #pragma unroll
    for (int m2 = 0; m2 < 2; ++m2) {
        const int m0 = (wv * 2 + m2) * 16 + quad * 4;
        const float4 bb = *(const float4*)(bias + m0);
        #pragma unroll
        for (int nt = 0; nt < 2; ++nt) {
            const int node = base + nt * 16 + nn;
            v4f a = acc[m2][nt];
            float x0 = fmaxf(a[0] + bb.x, 0.f);
            float x1 = fmaxf(a[1] + bb.y, 0.f);
            float x2 = fmaxf(a[2] + bb.z, 0.f);
            float x3 = fmaxf(a[3] + bb.w, 0.f);
            uint2 o;
            o.x = f2bf(x0) | (f2bf(x1) << 16);
            o.y = f2bf(x2) | (f2bf(x3) << 16);
            *(uint2*)(out + (size_t)node * F + m0) = o;
        }
    }
}

// ---------------- layer-2: hn2 = h @ Wn2 (bf16 out, row stride 64) ----------------

__global__ __launch_bounds__(256)
void gemm_hn2_kernel(const unsigned short* __restrict__ h,
                     const unsigned short* __restrict__ wfrag,
                     unsigned short* __restrict__ hn2) {
    const int lane = threadIdx.x & 63;
    const int wave = threadIdx.x >> 6;
    const int quad = lane >> 4;
    const int nn   = lane & 15;
    const int base = blockIdx.x * 128 + wave * 32;

    const int n0 = base + nn;
    const int n1 = base + 16 + nn;
    const size_t r0 = (size_t)min(n0, N_NODES - 1) * F;
    const size_t r1 = (size_t)min(n1, N_NODES - 1) * F;

    v4f acc[3][2];
    #pragma unroll
    for (int mt = 0; mt < 3; ++mt) { acc[mt][0] = (v4f)0.f; acc[mt][1] = (v4f)0.f; }

    #pragma unroll
    for (int kt = 0; kt < 4; ++kt) {
        const int koff = kt * 32 + quad * 8;
        v8s b0 = *(const v8s*)(h + r0 + koff);
        v8s b1 = *(const v8s*)(h + r1 + koff);
        #pragma unroll
        for (int mt = 0; mt < 3; ++mt) {
            v8s a = *(const v8s*)(wfrag + ((size_t)(mt * 4 + kt) * 64 + lane) * 8);
            acc[mt][0] = __builtin_amdgcn_mfma_f32_16x16x32_bf16(a, b0, acc[mt][0], 0, 0, 0);
            acc[mt][1] = __builtin_amdgcn_mfma_f32_16x16x32_bf16(a, b1, acc[mt][1], 0, 0, 0);
        }
    }

    #pragma unroll
    for (int mt = 0; mt < 3; ++mt) {
        const int m0 = mt * 16 + quad * 4;   // 0..47
        #pragma unroll
        for (int nt = 0; nt < 2; ++nt) {
            const int node = base + nt * 16 + nn;
            if (node >= N_NODES) continue;
            v4f a = acc[mt][nt];
            uint2 o;
            o.x = f2bf(a[0]) | (f2bf(a[1]) << 16);
            o.y = f2bf(a[2]) | (f2bf(a[3]) << 16);
            *(uint2*)(hn2 + (size_t)node * 64 + m0) = o;
        }
    }
}

// ---------------- fused layer 2: aggregate48(hn2) -> LDS, out = mean2 + h@Ws2 + b2 ----

__global__ __launch_bounds__(256)
void fused_final_kernel(const unsigned short* __restrict__ hn,
                        const int* __restrict__ deg,
                        const int* __restrict__ col,
                        const float* __restrict__ rdeg,
                        const unsigned short* __restrict__ h,
                        const unsigned short* __restrict__ wfrag,
                        const float* __restrict__ bias,
                        float* __restrict__ out) {
    __shared__ unsigned short M2[32][72];    // 32 x 64 mean2 tile, +8 pad

    const int wv   = threadIdx.x >> 6;
    const int lane = threadIdx.x & 63;
    const int sub8 = lane >> 3;
    const int li8  = lane & 7;
    const int base = blockIdx.x * 32;

    const uint4* hp4 = (const uint4*)hn;     // 8 uint4 per 128B row

    // ---- phase 1: 48-wide aggregate, 8 nodes per wave ----
    for (int j = 0; j < 8; ++j) {
        const int v   = base + wv * 8 + j;
        const int beg = v * CAP;
        const int end = beg + deg[v];
        const int dmax = max(end - 1, beg);

        float a0 = 0.f, a1 = 0.f, a2 = 0.f, a3 = 0.f;
        float a4 = 0.f, a5 = 0.f, a6 = 0.f, a7 = 0.f;

        int p = beg;
        int u = col[min(p + sub8, dmax)];
        #pragma unroll 2
        for (; p + 8 <= end; p += 8) {
            int un = col[min(p + 8 + sub8, dmax)];
            uint4 x = hp4[(size_t)u * 8 + li8];
            a0 += bfl(x.x); a1 += bfh(x.x);
            a2 += bfl(x.y); a3 += bfh(x.y);
            a4 += bfl(x.z); a5 += bfh(x.z);
            a6 += bfl(x.w); a7 += bfh(x.w);
            u = un;
        }
        if (p + sub8 < end) {
            uint4 x = hp4[(size_t)u * 8 + li8];
            a0 += bfl(x.x); a1 += bfh(x.x);
            a2 += bfl(x.y); a3 += bfh(x.y);
            a4 += bfl(x.z); a5 += bfh(x.z);
            a6 += bfl(x.w); a7 += bfh(x.w);
        }

        #pragma unroll
        for (int m = 8; m <= 32; m <<= 1) {
            a0 += __shfl_xor(a0, m, 64);
            a1 += __shfl_xor(a1, m, 64);
            a2 += __shfl_xor(a2, m, 64);
            a3 += __shfl_xor(a3, m, 64);
            a4 += __shfl_xor(a4, m, 64);
            a5 += __shfl_xor(a5, m, 64);
            a6 += __shfl_xor(a6, m, 64);
            a7 += __shfl_xor(a7, m, 64);
        }

        if (sub8 == 0) {
            const float r = rdeg[v];
            uint4 o;
            o.x = f2bf(a0 * r) | (f2bf(a1 * r) << 16);
            o.y = f2bf(a2 * r) | (f2bf(a3 * r) << 16);
            o.z = f2bf(a4 * r) | (f2bf(a5 * r) << 16);
            o.w = f2bf(a6 * r) | (f2bf(a7 * r) << 16);
            *(uint4*)&M2[wv * 8 + j][li8 * 8] = o;
        }
    }
    __syncthreads();

    // ---- phase 2: out = mean2 + h @ Ws2 + b2 (waves 0..2 handle mt 0..2) ----
    if (wv < 3) {
        const int quad = lane >> 4;
        const int nn   = lane & 15;
        const size_t r0 = (size_t)(base + nn) * F;
        const size_t r1 = (size_t)(base + 16 + nn) * F;

        v4f acc[2];
        acc[0] = (v4f)0.f; acc[1] = (v4f)0.f;

        #pragma unroll
        for (int kt = 0; kt < 4; ++kt) {
            const int koff = kt * 32 + quad * 8;
            v8s b0 = *(const v8s*)(h + r0 + koff);
            v8s b1 = *(const v8s*)(h + r1 + koff);
            v8s a = *(const v8s*)(wfrag + ((size_t)(wv * 4 + kt) * 64 + lane) * 8);
            acc[0] = __builtin_amdgcn_mfma_f32_16x16x32_bf16(a, b0, acc[0], 0, 0, 0);
            acc[1] = __builtin_amdgcn_mfma_f32_16x16x32_bf16(a, b1, acc[1], 0, 0, 0);
        }

        const int m0 = wv * 16 + quad * 4;   // 0..47, multiple of 4
        #pragma unroll
        for (int nt = 0; nt < 2; ++nt) {
            const int node = base + nt * 16 + nn;
            v4f a = acc[nt];
            uint2 mv = *(const uint2*)&M2[nt * 16 + nn][m0];
            float mf[4] = { bfl(mv.x), bfh(mv.x), bfl(mv.y), bfh(mv.y) };
            #pragma unroll
            for (int r = 0; r < 4; ++r) {
                int m = m0 + r;
                if (m < N_CLASSES)
                    out[(size_t)node * N_CLASSES + m] = a[r] + bias[m] + mf[r];
            }
        }
    }
}

// ---------------- launch ----------------

extern "C" void kernel_launch(void* const* d_in, const int* in_sizes, int n_in,
                              void* d_out, int out_size, void* d_ws, size_t ws_size,
                              hipStream_t stream) {
    const float* embed = (const float*)d_in[0];
    const float* Ws0   = (const float*)d_in[1];
    const float* Wn0   = (const float*)d_in[2];
    const float* b0    = (const float*)d_in[3];
    const float* Ws1   = (const float*)d_in[4];
    const float* Wn1   = (const float*)d_in[5];
    const float* b1    = (const float*)d_in[6];
    const float* Ws2   = (const float*)d_in[7];
    const float* Wn2   = (const float*)d_in[8];
    const float* b2    = (const float*)d_in[9];
    const int* input_nodes = (const int*)d_in[10];
    const int* src     = (const int*)d_in[11];
    const int* dst     = (const int*)d_in[12];
    float* out = (float*)d_out;

    char* ws = (char*)d_ws;
    size_t off = 0;
    auto alloc = [&](size_t bytes) -> void* {
        void* p = ws + off;
        off += (bytes + 255) & ~(size_t)255;
        return p;
    };
    int*            fillc    = (int*)           alloc(sizeof(int)   * N_NODES);
    float*          rdeg     = (float*)         alloc(sizeof(float) * N_NODES);
    int*            col      = (int*)           alloc(sizeof(int)   * (size_t)N_NODES * CAP);
    int*            gcnt     = (int*)           alloc(sizeof(int)   * NBKT);
    int2*           staged   = (int2*)          alloc(sizeof(int2)  * (size_t)NBKT * BCAP);
    unsigned short* h_a      = (unsigned short*)alloc(2 * (size_t)N_NODES * F);
    unsigned short* h_b      = (unsigned short*)alloc(2 * (size_t)N_NODES * F);
    unsigned short* wf0      = (unsigned short*)alloc(2 * 64 * 512);
    unsigned short* wf1      = (unsigned short*)alloc(2 * 64 * 512);
    unsigned short* wf2n     = (unsigned short*)alloc(2 * 12 * 512);
    unsigned short* wf2s     = (unsigned short*)alloc(2 * 12 * 512);
    (void)ws_size; (void)n_in; (void)in_sizes; (void)out_size;

    hipMemsetAsync(gcnt, 0, sizeof(int) * NBKT, stream);

    partition256_kernel<<<PART_B, PART_T, 0, stream>>>(src, dst, gcnt, staged);
    bucket_scatter_kernel<<<NBKT, 256, 0, stream>>>(staged, gcnt, fillc, rdeg, col);

    pack_w_kernel<<<64, 64, 0, stream>>>(Wn0, Ws0, F, wf0);
    pack_w_kernel<<<64, 64, 0, stream>>>(Wn1, Ws1, F, wf1);
    pack_w_single_kernel<<<12, 64, 0, stream>>>(Wn2, N_CLASSES, wf2n);
    pack_w_single_kernel<<<12, 64, 0, stream>>>(Ws2, N_CLASSES, wf2s);

    gather_embed_kernel<<<(N_NODES * (F / 4) + 255) / 256, 256, 0, stream>>>(embed, input_nodes, h_a);

    const int FUSED_B = N_NODES / 32;        // 3125, exact
    const int GEMM_B  = (N_NODES + 127) / 128;

    // layer 0: h_a -> h_b (fused aggregate + GEMM)
    fused_layer_kernel<<<FUSED_B, 256, 0, stream>>>(h_a, fillc, col, rdeg, wf0, b0, h_b);
    // layer 1: h_b -> h_a
    fused_layer_kernel<<<FUSED_B, 256, 0, stream>>>(h_b, fillc, col, rdeg, wf1, b1, h_a);
    // layer 2 (transform-first): hn2 = h_a @ Wn2 (rows 64, reuse h_b);
    // fused: mean2 = agg48(hn2) in LDS; out = mean2 + h_a @ Ws2 + b2
    gemm_hn2_kernel<<<GEMM_B, 256, 0, stream>>>(h_a, wf2n, h_b);
    fused_final_kernel<<<FUSED_B, 256, 0, stream>>>(h_b, fillc, col, rdeg, h_a, wf2s, b2, out);
}

// Round 8
// 383.215 us; speedup vs baseline: 1.4816x; 1.0093x over previous
//
#include <hip/hip_runtime.h>

#define N_NODES   100000
#define N_EDGES   1600000
#define F         128
#define N_CLASSES 47

#define NBKT      256
#define GDIV2     391            // nodes per bucket (391*256 = 100096 >= 100000)
#define BCAP      7000           // staged capacity per bucket (Poisson mean 6250, +9.5 sd)
#define CAP       64             // col slab capacity per node (Poisson(16): P(>64)~1e-20)
#define EPT       16             // edges per thread in partition (512 threads)
#define PART_T    512
#define EPB       (PART_T * EPT) // 8192 edges per block
#define PART_B    ((N_EDGES + EPB - 1) / EPB)

typedef unsigned int uint32;

typedef short  v8s __attribute__((ext_vector_type(8)));   // 8 x bf16 (MFMA A/B frag)
typedef float  v4f __attribute__((ext_vector_type(4)));   // MFMA C/D frag

// bf16 helpers (RNE)
__device__ __forceinline__ uint32 f2bf(float f) {
    uint32 u = __float_as_uint(f);
    return (u + 0x7FFFu + ((u >> 16) & 1u)) >> 16;
}
__device__ __forceinline__ float bfl(uint32 u) { return __uint_as_float(u << 16); }
__device__ __forceinline__ float bfh(uint32 u) { return __uint_as_float(u & 0xFFFF0000u); }

// ---------------- phase A: bin edges into 256 node-range buckets ----------------

__global__ __launch_bounds__(512)
void partition256_kernel(const int* __restrict__ src, const int* __restrict__ dst,
                         int* __restrict__ gcnt, int2* __restrict__ staged) {
    __shared__ int hist[NBKT];
    __shared__ int gbase[NBKT];
    const int tid = threadIdx.x;
    const int e0  = blockIdx.x * EPB;

    if (tid < NBKT) hist[tid] = 0;
    __syncthreads();

    int mys[EPT], myd[EPT];
    #pragma unroll
    for (int i = 0; i < EPT; ++i) {
        int e = e0 + i * PART_T + tid;
        bool val = (e < N_EDGES);
        mys[i] = val ? src[e] : 0;
        myd[i] = val ? dst[e] : -1;
        if (val) atomicAdd(&hist[myd[i] / GDIV2], 1);     // LDS atomic
    }
    __syncthreads();

    if (tid < NBKT) gbase[tid] = atomicAdd(&gcnt[tid], hist[tid]);  // 1 global atomic/bucket/block
    __syncthreads();
    if (tid < NBKT) hist[tid] = 0;                        // reuse as cursor
    __syncthreads();

    #pragma unroll
    for (int i = 0; i < EPT; ++i) {
        if (myd[i] >= 0) {
            int b = myd[i] / GDIV2;
            int r = atomicAdd(&hist[b], 1);               // LDS cursor rank
            int idx = gbase[b] + r;
            if (idx < BCAP)
                staged[(size_t)b * BCAP + idx] = make_int2(mys[i], myd[i]);
        }
    }
}

// ---------------- phase B: per-bucket scatter with LDS counters ----------------

__global__ __launch_bounds__(512)
void bucket_scatter_kernel(const int2* __restrict__ staged, const int* __restrict__ gcnt,
                           int* __restrict__ fillc, float* __restrict__ rdeg,
                           int* __restrict__ col) {
    __shared__ int cnt[GDIV2];
    const int b     = blockIdx.x;
    const int tid   = threadIdx.x;
    const int node0 = b * GDIV2;

    for (int i = tid; i < GDIV2; i += 512) cnt[i] = 0;
    __syncthreads();

    const int n = min(gcnt[b], BCAP);
    const int2* sp = staged + (size_t)b * BCAP;
    for (int i = tid; i < n; i += 512) {
        int2 sd = sp[i];
        int c = atomicAdd(&cnt[sd.y - node0], 1);         // LDS atomic
        if (c < CAP) col[(size_t)sd.y * CAP + c] = sd.x;
    }
    __syncthreads();

    for (int i = tid; i < GDIV2; i += 512) {
        int v = node0 + i;
        if (v < N_NODES) {
            int d = min(cnt[i], CAP);
            fillc[v] = d;
            rdeg[v]  = 1.0f / (float)max(d, 1);
        }
    }
}

// ---------------- merged weight pre-pack: all four frag buffers in one launch ----------------
// blocks 0..63: wf0 (Wn0|Ws0, nout=F, 8 kt); 64..127: wf1; 128..139: wf2n (Wn2, 4 kt);
// 140..151: wf2s (Ws2, 4 kt).

__global__ void pack_all_kernel(const float* __restrict__ Wn0, const float* __restrict__ Ws0,
                                const float* __restrict__ Wn1, const float* __restrict__ Ws1,
                                const float* __restrict__ Wn2, const float* __restrict__ Ws2,
                                unsigned short* __restrict__ wf0, unsigned short* __restrict__ wf1,
                                unsigned short* __restrict__ wf2n, unsigned short* __restrict__ wf2s) {
    const int blk  = blockIdx.x;
    const int lane = threadIdx.x;          // 64
    const int quad = lane >> 4;

    if (blk < 128) {                       // dual pack, K=256 (8 k-tiles)
        const float* Wn = (blk < 64) ? Wn0 : Wn1;
        const float* Ws = (blk < 64) ? Ws0 : Ws1;
        unsigned short* wfrag = (blk < 64) ? wf0 : wf1;
        int tile = blk & 63;
        int kt   = tile & 7;
        int mt   = tile >> 3;
        int m    = mt * 16 + (lane & 15);
        uint32 packed[4];
        #pragma unroll
        for (int jj = 0; jj < 4; ++jj) {
            uint32 lo = 0, hi = 0;
            #pragma unroll
            for (int b = 0; b < 2; ++b) {
                int k = kt * 32 + quad * 8 + jj * 2 + b;
                float w = (k < F) ? Wn[(size_t)k * F + m] : Ws[(size_t)(k - F) * F + m];
                if (b == 0) lo = f2bf(w); else hi = f2bf(w);
            }
            packed[jj] = lo | (hi << 16);
        }
        uint4 o = make_uint4(packed[0], packed[1], packed[2], packed[3]);
        *(uint4*)(wfrag + ((size_t)tile * 64 + lane) * 8) = o;
    } else {                               // single pack, K=128 (4 k-tiles), nout=47
        int bb = blk - 128;
        const float* W = (bb < 12) ? Wn2 : Ws2;
        unsigned short* wfrag = (bb < 12) ? wf2n : wf2s;
        int tile = (bb < 12) ? bb : (bb - 12);
        int kt   = tile & 3;
        int mt   = tile >> 2;
        int m    = mt * 16 + (lane & 15);
        uint32 packed[4];
        #pragma unroll
        for (int jj = 0; jj < 4; ++jj) {
            uint32 lo = 0, hi = 0;
            #pragma unroll
            for (int b = 0; b < 2; ++b) {
                int k = kt * 32 + quad * 8 + jj * 2 + b;
                float w = (m < N_CLASSES) ? W[(size_t)k * N_CLASSES + m] : 0.f;
                if (b == 0) lo = f2bf(w); else hi = f2bf(w);
            }
            packed[jj] = lo | (hi << 16);
        }
        uint4 o = make_uint4(packed[0], packed[1], packed[2], packed[3]);
        *(uint4*)(wfrag + ((size_t)tile * 64 + lane) * 8) = o;
    }
}

// ---------------- embedding gather: fp32 embed -> bf16 h ----------------

__global__ void gather_embed_kernel(const float* __restrict__ embed,
                                    const int* __restrict__ idx,
                                    unsigned short* __restrict__ h) {
    int i = blockIdx.x * blockDim.x + threadIdx.x;
    const int TOTAL = N_NODES * (F / 4);
    if (i < TOTAL) {
        int node = i >> 5;
        int c4 = i & 31;
        float4 v = ((const float4*)(embed + (size_t)idx[node] * F))[c4];
        uint2 o;
        o.x = f2bf(v.x) | (f2bf(v.y) << 16);
        o.y = f2bf(v.z) | (f2bf(v.w) << 16);
        ((uint2*)(h + (size_t)node * F))[c4] = o;
    }
}

// ---------------- fused layer (layers 0/1): aggregate 32 nodes -> LDS mean tile,
// then out = [mean|h] @ Wcat + b (+relu). Gather restructured: 4 independent
// col loads + 4 independent row loads per outer iteration (no prefetch chain)
// -> 4 rows in flight per lane; accumulation guarded, loads clamped (safe).
// Accumulation order identical to the serial loop (p, p+4, p+8, p+12).

__global__ __launch_bounds__(256)
void fused_layer_kernel(const unsigned short* __restrict__ h,
                        const int* __restrict__ deg,
                        const int* __restrict__ col,
                        const float* __restrict__ rdeg,
                        const unsigned short* __restrict__ wfrag,
                        const float* __restrict__ bias,
                        unsigned short* __restrict__ out) {
    __shared__ unsigned short Bm[32][136];   // 32 x 128 mean tile, +8 pad

    const int wv   = threadIdx.x >> 6;
    const int lane = threadIdx.x & 63;
    const int sub  = lane >> 4;
    const int li   = lane & 15;
    const int base = blockIdx.x * 32;        // grid 3125 * 32 = 100000 exact

    const uint4* hp4 = (const uint4*)h;

    // ---- phase 1: aggregate 8 nodes per wave ----
    for (int j = 0; j < 8; ++j) {
        const int v   = base + wv * 8 + j;
        const int beg = v * CAP;
        const int end = beg + deg[v];
        const int dmax = max(end - 1, beg);

        float a0 = 0.f, a1 = 0.f, a2 = 0.f, a3 = 0.f;
        float a4 = 0.f, a5 = 0.f, a6 = 0.f, a7 = 0.f;

        #pragma unroll 1
        for (int p = beg; p < end; p += 16) {
            const int e0i = p + sub, e1i = p + 4 + sub, e2i = p + 8 + sub, e3i = p + 12 + sub;
            int u0 = col[min(e0i, dmax)];
            int u1 = col[min(e1i, dmax)];
            int u2 = col[min(e2i, dmax)];
            int u3 = col[min(e3i, dmax)];
            uint4 x0 = hp4[(size_t)u0 * 16 + li];
            uint4 x1 = hp4[(size_t)u1 * 16 + li];
            uint4 x2 = hp4[(size_t)u2 * 16 + li];
            uint4 x3 = hp4[(size_t)u3 * 16 + li];
            if (e0i < end) {
                a0 += bfl(x0.x); a1 += bfh(x0.x); a2 += bfl(x0.y); a3 += bfh(x0.y);
                a4 += bfl(x0.z); a5 += bfh(x0.z); a6 += bfl(x0.w); a7 += bfh(x0.w);
            }
            if (e1i < end) {
                a0 += bfl(x1.x); a1 += bfh(x1.x); a2 += bfl(x1.y); a3 += bfh(x1.y);
                a4 += bfl(x1.z); a5 += bfh(x1.z); a6 += bfl(x1.w); a7 += bfh(x1.w);
            }
            if (e2i < end) {
                a0 += bfl(x2.x); a1 += bfh(x2.x); a2 += bfl(x2.y); a3 += bfh(x2.y);
                a4 += bfl(x2.z); a5 += bfh(x2.z); a6 += bfl(x2.w); a7 += bfh(x2.w);
            }
            if (e3i < end) {
                a0 += bfl(x3.x); a1 += bfh(x3.x); a2 += bfl(x3.y); a3 += bfh(x3.y);
                a4 += bfl(x3.z); a5 += bfh(x3.z); a6 += bfl(x3.w); a7 += bfh(x3.w);
            }
        }

        #pragma unroll
        for (int m = 16; m <= 32; m <<= 1) {
            a0 += __shfl_xor(a0, m, 64);
            a1 += __shfl_xor(a1, m, 64);
            a2 += __shfl_xor(a2, m, 64);
            a3 += __shfl_xor(a3, m, 64);
            a4 += __shfl_xor(a4, m, 64);
            a5 += __shfl_xor(a5, m, 64);
            a6 += __shfl_xor(a6, m, 64);
            a7 += __shfl_xor(a7, m, 64);
        }

        if (sub == 0) {
            const float r = rdeg[v];
            uint4 o;
            o.x = f2bf(a0 * r) | (f2bf(a1 * r) << 16);
            o.y = f2bf(a2 * r) | (f2bf(a3 * r) << 16);
            o.z = f2bf(a4 * r) | (f2bf(a5 * r) << 16);
            o.w = f2bf(a6 * r) | (f2bf(a7 * r) << 16);
            *(uint4*)&Bm[wv * 8 + j][li * 8] = o;
        }
    }
    __syncthreads();

    // ---- phase 2: GEMM, wave wv handles m-tiles {2wv, 2wv+1} ----
    const int quad = sub;
    const int nn   = li;
    const size_t r0 = (size_t)(base + nn) * F;
    const size_t r1 = (size_t)(base + 16 + nn) * F;

    v4f acc[2][2];
    acc[0][0] = (v4f)0.f; acc[0][1] = (v4f)0.f;
    acc[1][0] = (v4f)0.f; acc[1][1] = (v4f)0.f;

    #pragma unroll
    for (int kt = 0; kt < 8; ++kt) {
        const int koff = (kt & 3) * 32 + quad * 8;
        v8s b0, b1;
        if (kt < 4) {
            b0 = *(const v8s*)&Bm[nn][koff];
            b1 = *(const v8s*)&Bm[nn + 16][koff];
        } else {
            b0 = *(const v8s*)(h + r0 + koff);
            b1 = *(const v8s*)(h + r1 + koff);
        }
        #pragma unroll
        for (int m2 = 0; m2 < 2; ++m2) {
            const int mt = wv * 2 + m2;
            v8s a = *(const v8s*)(wfrag + ((size_t)(mt * 8 + kt) * 64 + lane) * 8);
            acc[m2][0] = __builtin_amdgcn_mfma_f32_16x16x32_bf16(a, b0, acc[m2][0], 0, 0, 0);
            acc[m2][1] = __builtin_amdgcn_mfma_f32_16x16x32_bf16(a, b1, acc[m2][1], 0, 0, 0);
        }
    }

    #pragma unroll
    for (int m2 = 0; m2 < 2; ++m2) {
        const int m0 = (wv * 2 + m2) * 16 + quad * 4;
        const float4 bb = *(const float4*)(bias + m0);
        #pragma unroll
        for (int nt = 0; nt < 2; ++nt) {
            const int node = base + nt * 16 + nn;
            v4f a = acc[m2][nt];
            float x0 = fmaxf(a[0] + bb.x, 0.f);
            float x1 = fmaxf(a[1] + bb.y, 0.f);
            float x2 = fmaxf(a[2] + bb.z, 0.f);
            float x3 = fmaxf(a[3] + bb.w, 0.f);
            uint2 o;
            o.x = f2bf(x0) | (f2bf(x1) << 16);
            o.y = f2bf(x2) | (f2bf(x3) << 16);
            *(uint2*)(out + (size_t)node * F + m0) = o;
        }
    }
}

// ---------------- layer-2: hn2 = h @ Wn2 (bf16 out, row stride 64) ----------------

__global__ __launch_bounds__(256)
void gemm_hn2_kernel(const unsigned short* __restrict__ h,
                     const unsigned short* __restrict__ wfrag,
                     unsigned short* __restrict__ hn2) {
    const int lane = threadIdx.x & 63;
    const int wave = threadIdx.x >> 6;
    const int quad = lane >> 4;
    const int nn   = lane & 15;
    const int base = blockIdx.x * 128 + wave * 32;

    const int n0 = base + nn;
    const int n1 = base + 16 + nn;
    const size_t r0 = (size_t)min(n0, N_NODES - 1) * F;
    const size_t r1 = (size_t)min(n1, N_NODES - 1) * F;

    v4f acc[3][2];
    #pragma unroll
    for (int mt = 0; mt < 3; ++mt) { acc[mt][0] = (v4f)0.f; acc[mt][1] = (v4f)0.f; }

    #pragma unroll
    for (int kt = 0; kt < 4; ++kt) {
        const int koff = kt * 32 + quad * 8;
        v8s b0 = *(const v8s*)(h + r0 + koff);
        v8s b1 = *(const v8s*)(h + r1 + koff);
        #pragma unroll
        for (int mt = 0; mt < 3; ++mt) {
            v8s a = *(const v8s*)(wfrag + ((size_t)(mt * 4 + kt) * 64 + lane) * 8);
            acc[mt][0] = __builtin_amdgcn_mfma_f32_16x16x32_bf16(a, b0, acc[mt][0], 0, 0, 0);
            acc[mt][1] = __builtin_amdgcn_mfma_f32_16x16x32_bf16(a, b1, acc[mt][1], 0, 0, 0);
        }
    }

    #pragma unroll
    for (int mt = 0; mt < 3; ++mt) {
        const int m0 = mt * 16 + quad * 4;   // 0..47
        #pragma unroll
        for (int nt = 0; nt < 2; ++nt) {
            const int node = base + nt * 16 + nn;
            if (node >= N_NODES) continue;
            v4f a = acc[mt][nt];
            uint2 o;
            o.x = f2bf(a[0]) | (f2bf(a[1]) << 16);
            o.y = f2bf(a[2]) | (f2bf(a[3]) << 16);
            *(uint2*)(hn2 + (size_t)node * 64 + m0) = o;
        }
    }
}

// ---------------- fused layer 2: aggregate48(hn2) -> LDS, out = mean2 + h@Ws2 + b2 ----
// Gather restructured: 2 independent col+row loads per outer iteration.

__global__ __launch_bounds__(256)
void fused_final_kernel(const unsigned short* __restrict__ hn,
                        const int* __restrict__ deg,
                        const int* __restrict__ col,
                        const float* __restrict__ rdeg,
                        const unsigned short* __restrict__ h,
                        const unsigned short* __restrict__ wfrag,
                        const float* __restrict__ bias,
                        float* __restrict__ out) {
    __shared__ unsigned short M2[32][72];    // 32 x 64 mean2 tile, +8 pad

    const int wv   = threadIdx.x >> 6;
    const int lane = threadIdx.x & 63;
    const int sub8 = lane >> 3;
    const int li8  = lane & 7;
    const int base = blockIdx.x * 32;

    const uint4* hp4 = (const uint4*)hn;     // 8 uint4 per 128B row

    // ---- phase 1: 48-wide aggregate, 8 nodes per wave ----
    for (int j = 0; j < 8; ++j) {
        const int v   = base + wv * 8 + j;
        const int beg = v * CAP;
        const int end = beg + deg[v];
        const int dmax = max(end - 1, beg);

        float a0 = 0.f, a1 = 0.f, a2 = 0.f, a3 = 0.f;
        float a4 = 0.f, a5 = 0.f, a6 = 0.f, a7 = 0.f;

        #pragma unroll 1
        for (int p = beg; p < end; p += 16) {
            const int e0i = p + sub8, e1i = p + 8 + sub8;
            int u0 = col[min(e0i, dmax)];
            int u1 = col[min(e1i, dmax)];
            uint4 x0 = hp4[(size_t)u0 * 8 + li8];
            uint4 x1 = hp4[(size_t)u1 * 8 + li8];
            if (e0i < end) {
                a0 += bfl(x0.x); a1 += bfh(x0.x); a2 += bfl(x0.y); a3 += bfh(x0.y);
                a4 += bfl(x0.z); a5 += bfh(x0.z); a6 += bfl(x0.w); a7 += bfh(x0.w);
            }
            if (e1i < end) {
                a0 += bfl(x1.x); a1 += bfh(x1.x); a2 += bfl(x1.y); a3 += bfh(x1.y);
                a4 += bfl(x1.z); a5 += bfh(x1.z); a6 += bfl(x1.w); a7 += bfh(x1.w);
            }
        }

        #pragma unroll
        for (int m = 8; m <= 32; m <<= 1) {
            a0 += __shfl_xor(a0, m, 64);
            a1 += __shfl_xor(a1, m, 64);
            a2 += __shfl_xor(a2, m, 64);
            a3 += __shfl_xor(a3, m, 64);
            a4 += __shfl_xor(a4, m, 64);
            a5 += __shfl_xor(a5, m, 64);
            a6 += __shfl_xor(a6, m, 64);
            a7 += __shfl_xor(a7, m, 64);
        }

        if (sub8 == 0) {
            const float r = rdeg[v];
            uint4 o;
            o.x = f2bf(a0 * r) | (f2bf(a1 * r) << 16);
            o.y = f2bf(a2 * r) | (f2bf(a3 * r) << 16);
            o.z = f2bf(a4 * r) | (f2bf(a5 * r) << 16);
            o.w = f2bf(a6 * r) | (f2bf(a7 * r) << 16);
            *(uint4*)&M2[wv * 8 + j][li8 * 8] = o;
        }
    }
    __syncthreads();

    // ---- phase 2: out = mean2 + h @ Ws2 + b2 (waves 0..2 handle mt 0..2) ----
    if (wv < 3) {
        const int quad = lane >> 4;
        const int nn   = lane & 15;
        const size_t r0 = (size_t)(base + nn) * F;
        const size_t r1 = (size_t)(base + 16 + nn) * F;

        v4f acc[2];
        acc[0] = (v4f)0.f; acc[1] = (v4f)0.f;

        #pragma unroll
        for (int kt = 0; kt < 4; ++kt) {
            const int koff = kt * 32 + quad * 8;
            v8s b0 = *(const v8s*)(h + r0 + koff);
            v8s b1 = *(const v8s*)(h + r1 + koff);
            v8s a = *(const v8s*)(wfrag + ((size_t)(wv * 4 + kt) * 64 + lane) * 8);
            acc[0] = __builtin_amdgcn_mfma_f32_16x16x32_bf16(a, b0, acc[0], 0, 0, 0);
            acc[1] = __builtin_amdgcn_mfma_f32_16x16x32_bf16(a, b1, acc[1], 0, 0, 0);
        }

        const int m0 = wv * 16 + quad * 4;   // 0..47, multiple of 4
        #pragma unroll
        for (int nt = 0; nt < 2; ++nt) {
            const int node = base + nt * 16 + nn;
            v4f a = acc[nt];
            uint2 mv = *(const uint2*)&M2[nt * 16 + nn][m0];
            float mf[4] = { bfl(mv.x), bfh(mv.x), bfl(mv.y), bfh(mv.y) };
            #pragma unroll
            for (int r = 0; r < 4; ++r) {
                int m = m0 + r;
                if (m < N_CLASSES)
                    out[(size_t)node * N_CLASSES + m] = a[r] + bias[m] + mf[r];
            }
        }
    }
}

// ---------------- launch ----------------

extern "C" void kernel_launch(void* const* d_in, const int* in_sizes, int n_in,
                              void* d_out, int out_size, void* d_ws, size_t ws_size,
                              hipStream_t stream) {
    const float* embed = (const float*)d_in[0];
    const float* Ws0   = (const float*)d_in[1];
    const float* Wn0   = (const float*)d_in[2];
    const float* b0    = (const float*)d_in[3];
    const float* Ws1   = (const float*)d_in[4];
    const float* Wn1   = (const float*)d_in[5];
    const float* b1    = (const float*)d_in[6];
    const float* Ws2   = (const float*)d_in[7];
    const float* Wn2   = (const float*)d_in[8];
    const float* b2    = (const float*)d_in[9];
    const int* input_nodes = (const int*)d_in[10];
    const int* src     = (const int*)d_in[11];
    const int* dst     = (const int*)d_in[12];
    float* out = (float*)d_out;

    char* ws = (char*)d_ws;
    size_t off = 0;
    auto alloc = [&](size_t bytes) -> void* {
        void* p = ws + off;
        off += (bytes + 255) & ~(size_t)255;
        return p;
    };
    int*            fillc    = (int*)           alloc(sizeof(int)   * N_NODES);
    float*          rdeg     = (float*)         alloc(sizeof(float) * N_NODES);
    int*            col      = (int*)           alloc(sizeof(int)   * (size_t)N_NODES * CAP);
    int*            gcnt     = (int*)           alloc(sizeof(int)   * NBKT);
    int2*           staged   = (int2*)          alloc(sizeof(int2)  * (size_t)NBKT * BCAP);
    unsigned short* h_a      = (unsigned short*)alloc(2 * (size_t)N_NODES * F);
    unsigned short* h_b      = (unsigned short*)alloc(2 * (size_t)N_NODES * F);
    unsigned short* wf0      = (unsigned short*)alloc(2 * 64 * 512);
    unsigned short* wf1      = (unsigned short*)alloc(2 * 64 * 512);
    unsigned short* wf2n     = (unsigned short*)alloc(2 * 12 * 512);
    unsigned short* wf2s     = (unsigned short*)alloc(2 * 12 * 512);
    (void)ws_size; (void)n_in; (void)in_sizes; (void)out_size;

    hipMemsetAsync(gcnt, 0, sizeof(int) * NBKT, stream);

    partition256_kernel<<<PART_B, PART_T, 0, stream>>>(src, dst, gcnt, staged);
    bucket_scatter_kernel<<<NBKT, 512, 0, stream>>>(staged, gcnt, fillc, rdeg, col);

    pack_all_kernel<<<152, 64, 0, stream>>>(Wn0, Ws0, Wn1, Ws1, Wn2, Ws2, wf0, wf1, wf2n, wf2s);

    gather_embed_kernel<<<(N_NODES * (F / 4) + 255) / 256, 256, 0, stream>>>(embed, input_nodes, h_a);

    const int FUSED_B = N_NODES / 32;        // 3125, exact
    const int GEMM_B  = (N_NODES + 127) / 128;

    // layer 0: h_a -> h_b (fused aggregate + GEMM)
    fused_layer_kernel<<<FUSED_B, 256, 0, stream>>>(h_a, fillc, col, rdeg, wf0, b0, h_b);
    // layer 1: h_b -> h_a
    fused_layer_kernel<<<FUSED_B, 256, 0, stream>>>(h_b, fillc, col, rdeg, wf1, b1, h_a);
    // layer 2 (transform-first): hn2 = h_a @ Wn2 (rows 64, reuse h_b);
    // fused: mean2 = agg48(hn2) in LDS; out = mean2 + h_a @ Ws2 + b2
    gemm_hn2_kernel<<<GEMM_B, 256, 0, stream>>>(h_a, wf2n, h_b);
    fused_final_kernel<<<FUSED_B, 256, 0, stream>>>(h_b, fillc, col, rdeg, h_a, wf2s, b2, out);
}